// Round 3
// baseline (762.340 us; speedup 1.0000x reference)
//
#include <hip/hip_runtime.h>
#include <hip/hip_bf16.h>
#include <hip/hip_fp8.h>
#include <hip/hip_fp16.h>

#define N_NODESC 100000
#define N_EDGESC 1600000
#define FEATC 64
#define HEADSC 8
#define BATCHC 64
#define MAXLENC 2048
#define NBUCK 500          // 500 buckets x exactly 200 dst nodes
#define BSZ 200
#define P3_EDGES 8192      // edges per k_csort workgroup (1024 thr x 8)
#define K1B 391            // k_pre blocks doing the node transform

typedef float f32x2 __attribute__((ext_vector_type(2)));

__device__ __forceinline__ float b2f(unsigned short u){
  union { unsigned u; float f; } c; c.u = ((unsigned)u) << 16; return c.f;
}
__device__ __forceinline__ unsigned short f2b(float f){
  union { float f; unsigned u; } c; c.f = f;
  unsigned r = c.u + 0x7fffu + ((c.u >> 16) & 1u);
  return (unsigned short)(r >> 16);
}
__device__ __forceinline__ int clampi(int v, int lo, int hi){
  return v < lo ? lo : (v > hi ? hi : v);
}
__device__ __forceinline__ void unpack8(uint4 v, float* o){
  o[0] = b2f((unsigned short)(v.x & 0xffff)); o[1] = b2f((unsigned short)(v.x >> 16));
  o[2] = b2f((unsigned short)(v.y & 0xffff)); o[3] = b2f((unsigned short)(v.y >> 16));
  o[4] = b2f((unsigned short)(v.z & 0xffff)); o[5] = b2f((unsigned short)(v.z >> 16));
  o[6] = b2f((unsigned short)(v.w & 0xffff)); o[7] = b2f((unsigned short)(v.w >> 16));
}
// 4 x fp8(e4m3, OCP on gfx950) packed in a dword -> 4 floats via v_cvt_pk_f32_fp8
__device__ __forceinline__ void cvt4(unsigned v, float* o){
  f32x2 lo = __builtin_amdgcn_cvt_pk_f32_fp8((int)v, false);
  f32x2 hi = __builtin_amdgcn_cvt_pk_f32_fp8((int)v, true);
  o[0] = lo.x; o[1] = lo.y; o[2] = hi.x; o[3] = hi.y;
}

// ---- K_pre: heterogeneous grid. Blocks [0,K1B): xw=x@W -> fp8 + a_src(fp16)
// + a_dst(fp32). Blocks [K1B,..): coarse 500-bin histogram of dst. ----
__global__ __launch_bounds__(256) void k_pre(
    const unsigned short* __restrict__ x, const unsigned short* __restrict__ W,
    const unsigned short* __restrict__ attS, const unsigned short* __restrict__ attD,
    const int* __restrict__ ei,
    unsigned char* __restrict__ xw8, __half* __restrict__ a_srch,
    float* __restrict__ a_dst, int* __restrict__ cc)
{
  __shared__ float Wsf[64 * 64];
  __shared__ float as_s[64];
  __shared__ float ad_s[64];
  __shared__ int hh[NBUCK];
  int t = threadIdx.x;

  if (blockIdx.x >= K1B) {
    // ---- coarse histogram part ----
    for (int i = t; i < NBUCK; i += 256) hh[i] = 0;
    __syncthreads();
    int g = (blockIdx.x - K1B) * 256 + t;
    if (g < N_EDGESC / 4) {
      int4 d = ((const int4*)(ei + N_EDGESC))[g];
      atomicAdd(&hh[clampi(d.x, 0, N_NODESC - 1) / BSZ], 1);
      atomicAdd(&hh[clampi(d.y, 0, N_NODESC - 1) / BSZ], 1);
      atomicAdd(&hh[clampi(d.z, 0, N_NODESC - 1) / BSZ], 1);
      atomicAdd(&hh[clampi(d.w, 0, N_NODESC - 1) / BSZ], 1);
    }
    __syncthreads();
    for (int i = t; i < NBUCK; i += 256) if (hh[i]) atomicAdd(&cc[i], hh[i]);
    return;
  }

  // ---- node transform part ----
  for (int i = t; i < 4096; i += 256) Wsf[i] = b2f(W[i]);
  if (t < 64) { as_s[t] = b2f(attS[t]); ad_s[t] = b2f(attD[t]); }
  __syncthreads();

  int g    = t & 3;
  int slot = t >> 2;
  int n0 = blockIdx.x * 256 + slot * 4;

  float acc[4][16];
  #pragma unroll
  for (int j = 0; j < 4; j++)
    #pragma unroll
    for (int c = 0; c < 16; c++) acc[j][c] = 0.f;

  const float4* Ws4 = (const float4*)Wsf;
  for (int i = 0; i < 8; i++) {
    float xu[4][8];
    #pragma unroll
    for (int j = 0; j < 4; j++) {
      int n = n0 + j;
      uint4 v = make_uint4(0u,0u,0u,0u);
      if (n < N_NODESC) v = ((const uint4*)(x + (size_t)n * 64))[i];
      unpack8(v, xu[j]);
    }
    #pragma unroll
    for (int u = 0; u < 8; u++) {
      int k = i * 8 + u;
      float4 w0 = Ws4[k * 16 + g * 4 + 0];
      float4 w1 = Ws4[k * 16 + g * 4 + 1];
      float4 w2 = Ws4[k * 16 + g * 4 + 2];
      float4 w3 = Ws4[k * 16 + g * 4 + 3];
      #pragma unroll
      for (int j = 0; j < 4; j++) {
        float xk = xu[j][u];
        acc[j][ 0] += xk * w0.x; acc[j][ 1] += xk * w0.y;
        acc[j][ 2] += xk * w0.z; acc[j][ 3] += xk * w0.w;
        acc[j][ 4] += xk * w1.x; acc[j][ 5] += xk * w1.y;
        acc[j][ 6] += xk * w1.z; acc[j][ 7] += xk * w1.w;
        acc[j][ 8] += xk * w2.x; acc[j][ 9] += xk * w2.y;
        acc[j][10] += xk * w2.z; acc[j][11] += xk * w2.w;
        acc[j][12] += xk * w3.x; acc[j][13] += xk * w3.y;
        acc[j][14] += xk * w3.z; acc[j][15] += xk * w3.w;
      }
    }
  }

  #pragma unroll
  for (int j = 0; j < 4; j++) {
    int n = n0 + j;
    if (n >= N_NODESC) break;
    union { unsigned u[4]; unsigned char b[16]; } pk;
    #pragma unroll
    for (int c = 0; c < 16; c++)
      pk.b[c] = (unsigned char)__hip_fp8_e4m3(acc[j][c]).__x;
    uint4 o; o.x = pk.u[0]; o.y = pk.u[1]; o.z = pk.u[2]; o.w = pk.u[3];
    *((uint4*)(xw8 + (size_t)n * 64 + g * 16)) = o;

    #pragma unroll
    for (int hl = 0; hl < 2; hl++) {
      int h = g * 2 + hl;
      float sa = 0.f, sd = 0.f;
      #pragma unroll
      for (int c = 0; c < 8; c++) {
        sa += acc[j][hl * 8 + c] * as_s[h * 8 + c];
        sd += acc[j][hl * 8 + c] * ad_s[h * 8 + c];
      }
      a_srch[n * 8 + h] = __float2half(sa);
      a_dst[n * 8 + h] = sd;
    }
  }
}

// ---- coarse scatter (1024 thr, 8192 edges/wg): self-scan of cc -> bstart,
// LDS counting-sort by bucket, contiguous run writes via zero-based gcur.
// Block 0 additionally publishes the exclusive bucket-prefix to boff[] so
// k_aggf doesn't have to re-scan cc. ----
__global__ __launch_bounds__(1024) void k_csort(const int* __restrict__ ei,
                                                const int* __restrict__ cc,
                                                int* __restrict__ gcur,
                                                unsigned* __restrict__ cs,
                                                int* __restrict__ boff) {
  __shared__ int bst[512];
  __shared__ int h[NBUCK], lst[NBUCK], lcur[NBUCK], gb[NBUCK];
  __shared__ int sc[512];
  __shared__ unsigned sorted[P3_EDGES];
  __shared__ unsigned short sbk[P3_EDGES];
  int t = threadIdx.x;
  int base = blockIdx.x * P3_EDGES;
  for (int i = t; i < NBUCK; i += 1024) h[i] = 0;
  int myc = 0;
  if (t < 512) { myc = (t < NBUCK) ? cc[t] : 0; bst[t] = myc; }
  __syncthreads();
  for (int off = 1; off < 512; off <<= 1) {
    int v = 0;
    if (t < 512) { v = bst[t]; if (t >= off) v += bst[t - off]; }
    __syncthreads();
    if (t < 512) bst[t] = v;
    __syncthreads();
  }
  if (blockIdx.x == 0 && t < NBUCK) boff[t] = bst[t] - myc;
  unsigned pk[8]; int bk[8];
  #pragma unroll
  for (int k = 0; k < 8; k++) {
    int idx = base + k * 1024 + t;
    bk[k] = -1;
    if (idx < N_EDGESC) {
      int s = clampi(ei[idx], 0, N_NODESC - 1);
      int d = clampi(ei[N_EDGESC + idx], 0, N_NODESC - 1);
      int b = d / BSZ;
      pk[k] = (unsigned)s | ((unsigned)(d - b * BSZ) << 17);
      bk[k] = b;
      atomicAdd(&h[b], 1);
    }
  }
  __syncthreads();
  if (t < 512) sc[t] = (t < NBUCK) ? h[t] : 0;
  __syncthreads();
  for (int off = 1; off < 512; off <<= 1) {
    int v = 0;
    if (t < 512) { v = sc[t]; if (t >= off) v += sc[t - off]; }
    __syncthreads();
    if (t < 512) sc[t] = v;
    __syncthreads();
  }
  if (t < NBUCK) {
    int ex = sc[t] - h[t];
    lst[t] = ex; lcur[t] = ex;
    if (h[t]) gb[t] = (bst[t] - myc) + atomicAdd(&gcur[t], h[t]);
  }
  __syncthreads();
  #pragma unroll
  for (int k = 0; k < 8; k++) if (bk[k] >= 0) {
    int p = atomicAdd(&lcur[bk[k]], 1);
    sorted[p] = pk[k];
    sbk[p] = (unsigned short)bk[k];
  }
  __syncthreads();
  int cnt = N_EDGESC - base; if (cnt > P3_EDGES) cnt = P3_EDGES;
  #pragma unroll
  for (int k = 0; k < 8; k++) {
    int i = k * 1024 + t;
    if (i < cnt) {
      int b = sbk[i];
      cs[gb[b] + (i - lst[b])] = sorted[i];
    }
  }
}

// ---- K_aggf v4: one 1024-thread WG per bucket (200 dsts). NO within-bucket
// sort: edges streamed straight from cs[] in arbitrary order and accumulated
// into LDS via ds_add_f32 (fire-and-forget atomics). acc[200][68-pad] 54KB +
// den/ad[200][9-pad]. Zero cross-lane ops, zero inter-iteration register
// dependencies -> gather loads from all groups pipeline freely; 68.8KB LDS
// -> 2 WG/CU = 32 waves (full occupancy). Self edge folded into init
// (den=selfw, acc=selfw*x_self). Random dl order => same-address atomic
// serialization is rare; stride-68 rows keep banks spread (68%32=4).
__global__ __launch_bounds__(1024, 2) void k_aggf(
    const __half* __restrict__ a_srch, const float* __restrict__ a_dst,
    const unsigned char* __restrict__ xw8, const unsigned* __restrict__ cs,
    const int* __restrict__ cc, const int* __restrict__ boff,
    const unsigned short* __restrict__ bias, unsigned short* __restrict__ nembh)
{
  __shared__ float sacc[BSZ * 68];
  __shared__ float sden[BSZ * 9];
  __shared__ float sad[BSZ * 9];
  int t = threadIdx.x;
  int b = blockIdx.x;
  int base = boff[b];
  int cnt  = cc[b];

  // phase 1: load a_dst rows into LDS + self weight into den
  for (int i = t; i < BSZ * 8; i += 1024) {
    int dl = i >> 3, h = i & 7;
    int dst = b * BSZ + dl;
    float adv = a_dst[dst * 8 + h];
    float sa  = __half2float(a_srch[dst * 8 + h]);
    sad[dl * 9 + h] = adv;
    float zs = sa + adv;
    sden[dl * 9 + h] = __expf(fmaxf(zs, 0.2f * zs));
  }
  __syncthreads();
  // phase 2: acc = selfw * x_self (covers all 200x64; no zeroing pass needed)
  for (int i = t; i < BSZ * 16; i += 1024) {
    int dl = i >> 4, q = i & 15, h = q >> 1;
    int dst = b * BSZ + dl;
    unsigned xr = *(const unsigned*)(xw8 + ((unsigned)dst << 6) + (q << 2));
    float xv[4]; cvt4(xr, xv);
    float sw = sden[dl * 9 + h];
    int ab = dl * 68 + q * 4;
    sacc[ab + 0] = sw * xv[0]; sacc[ab + 1] = sw * xv[1];
    sacc[ab + 2] = sw * xv[2]; sacc[ab + 3] = sw * xv[3];
  }
  __syncthreads();

  // hot loop: 8 edges per wave-iteration, lane = (edge slot e, head h).
  // Head h owns channels 8h..8h+7 -> per-lane weight is the one it needs.
  int wv = t >> 6, l = t & 63, e = l >> 3, h = l & 7;
  int ngroups = (cnt + 7) >> 3;
  #pragma unroll 2
  for (int gp = wv; gp < ngroups; gp += 16) {
    int ei_ = gp * 8 + e;
    bool valid = ei_ < cnt;
    int rd = valid ? ei_ : (cnt - 1);          // clamp: stays inside bucket
    unsigned pk = cs[base + rd];
    int src = (int)(pk & 0x1FFFFu);
    int dl  = (int)(pk >> 17);
    float av = __half2float(a_srch[src * 8 + h]);
    uint2 xr = *(const uint2*)(xw8 + ((unsigned)src << 6) + (h << 3));
    float z = av + sad[dl * 9 + h];
    float w = __expf(fmaxf(z, 0.2f * z));
    if (!valid) w = 0.f;
    atomicAdd(&sden[dl * 9 + h], w);
    float x0[4], x1[4]; cvt4(xr.x, x0); cvt4(xr.y, x1);
    int ab = dl * 68 + h * 8;
    atomicAdd(&sacc[ab + 0], w * x0[0]); atomicAdd(&sacc[ab + 1], w * x0[1]);
    atomicAdd(&sacc[ab + 2], w * x0[2]); atomicAdd(&sacc[ab + 3], w * x0[3]);
    atomicAdd(&sacc[ab + 4], w * x1[0]); atomicAdd(&sacc[ab + 5], w * x1[1]);
    atomicAdd(&sacc[ab + 6], w * x1[2]); atomicAdd(&sacc[ab + 7], w * x1[3]);
  }
  __syncthreads();

  // epilogue: divide, bias, relu, pack bf16, store (fully parallel)
  for (int i = t; i < BSZ * 16; i += 1024) {
    int dl = i >> 4, q = i & 15, h = q >> 1;
    int dst = b * BSZ + dl;
    float4 a = *(float4*)&sacc[dl * 68 + q * 4];   // 272B rows: 16B aligned
    float inv = __builtin_amdgcn_rcpf(sden[dl * 9 + h]);
    uint2 bb = ((const uint2*)bias)[q];
    float v0 = a.x * inv + b2f((unsigned short)(bb.x & 0xffff));
    float v1 = a.y * inv + b2f((unsigned short)(bb.x >> 16));
    float v2 = a.z * inv + b2f((unsigned short)(bb.y & 0xffff));
    float v3 = a.w * inv + b2f((unsigned short)(bb.y >> 16));
    v0 = fmaxf(v0, 0.f); v1 = fmaxf(v1, 0.f);
    v2 = fmaxf(v2, 0.f); v3 = fmaxf(v3, 0.f);
    uint2 o;
    o.x = (unsigned)f2b(v0) | ((unsigned)f2b(v1) << 16);
    o.y = (unsigned)f2b(v2) | ((unsigned)f2b(v3) << 16);
    ((uint2*)nembh)[(size_t)dst * 16 + q] = o;
  }
}

// ---- K6: padded gather from bf16 nemb -> fp32 out + seq_lengths tail ----
__global__ __launch_bounds__(256) void k6_gather(
    const unsigned short* __restrict__ nembh, const int* __restrict__ traj,
    const int* __restrict__ lens, float* __restrict__ out)
{
  int gid = blockIdx.x * 256 + threadIdx.x;
  if (gid < BATCHC * MAXLENC * 16) {
    int b = gid >> 15;
    int rem = gid & 32767;
    int l = rem >> 4;
    int ch = rem & 15;
    int len = clampi(lens[b], 0, MAXLENC);
    float4 val = make_float4(0.f, 0.f, 0.f, 0.f);
    if (l < len) {
      int node = clampi(traj[b * MAXLENC + l], 0, N_NODESC - 1);
      uint2 q = ((const uint2*)nembh)[(size_t)node * 16 + ch];
      val = make_float4(b2f((unsigned short)(q.x & 0xffff)),
                        b2f((unsigned short)(q.x >> 16)),
                        b2f((unsigned short)(q.y & 0xffff)),
                        b2f((unsigned short)(q.y >> 16)));
    }
    ((float4*)out)[gid] = val;
  }
  if (gid < BATCHC) {
    out[(size_t)BATCHC * MAXLENC * FEATC + gid] = (float)lens[gid];
  }
}

extern "C" void kernel_launch(void* const* d_in, const int* in_sizes, int n_in,
                              void* d_out, int out_size, void* d_ws, size_t ws_size,
                              hipStream_t stream) {
  const unsigned short* x    = (const unsigned short*)d_in[0];
  const unsigned short* W    = (const unsigned short*)d_in[1];
  const unsigned short* attS = (const unsigned short*)d_in[2];
  const unsigned short* attD = (const unsigned short*)d_in[3];
  const unsigned short* bias = (const unsigned short*)d_in[4];
  const int* ei   = (const int*)d_in[5];
  const int* traj = (const int*)d_in[6];
  const int* lens = (const int*)d_in[7];
  float* out = (float*)d_out;

  // workspace (float units, max 9.9M floats = 39.6 MB; under proven size):
  //  [0, 1.6M)        xw fp8 (6.4M bytes)
  //  [3.2M, 3.6M)     a_src fp16 (800k half)
  //  [4.0M, 4.8M)     a_dst fp32
  //  [4.9M, +512)     ccounts (500)
  //  [+512, +1024)    gcur (500, zero-based)   -- one memset covers both
  //  [+1024, +1536)   boff (500, written by k_csort block 0)
  //  [5.0M, 6.6M)     cs (packed uint, 1.6M)
  //  [6.7M, 9.9M)     nemb bf16 (6.4M ushort)
  float* F = (float*)d_ws;
  unsigned char* xw8 = (unsigned char*)d_ws;
  __half* a_srch = (__half*)(F + 3200000);
  float* a_dst   = F + 4000000;
  int* ccounts   = (int*)(F + 4900000);
  int* gcur      = (int*)(F + 4900000) + 512;
  int* boff      = (int*)(F + 4900000) + 1024;
  unsigned* cs   = (unsigned*)(F + 5000000);
  unsigned short* nembh = (unsigned short*)(F + 6700000);

  hipMemsetAsync(ccounts, 0, 1024 * sizeof(int), stream);
  k_pre<<<K1B + (N_EDGESC / 4 + 255) / 256, 256, 0, stream>>>(
      x, W, attS, attD, ei, xw8, a_srch, a_dst, ccounts);
  k_csort<<<(N_EDGESC + P3_EDGES - 1) / P3_EDGES, 1024, 0, stream>>>(ei, ccounts, gcur, cs, boff);
  k_aggf<<<NBUCK, 1024, 0, stream>>>(a_srch, a_dst, xw8, cs, ccounts, boff, bias, nembh);
  k6_gather<<<(BATCHC * MAXLENC * 16 + 255) / 256, 256, 0, stream>>>(nembh, traj, lens, out);
}

// Round 6
// 200.797 us; speedup vs baseline: 3.7966x; 3.7966x over previous
//
#include <hip/hip_runtime.h>
#include <hip/hip_bf16.h>
#include <hip/hip_fp8.h>
#include <hip/hip_fp16.h>

#define N_NODESC 100000
#define N_EDGESC 1600000
#define FEATC 64
#define HEADSC 8
#define BATCHC 64
#define MAXLENC 2048
#define NBUCK 500          // 500 buckets x exactly 200 dst nodes
#define BSZ 200
#define HSZ 100            // dsts per k_aggf workgroup (half bucket)
#define CAPH 3072          // LDS edge capacity per half-bucket (mean 1600, sigma ~40)
#define P3_EDGES 8192      // edges per k_csort workgroup (1024 thr x 8)
#define K1B 391            // k_pre blocks doing the node transform

typedef float f32x2 __attribute__((ext_vector_type(2)));

__device__ __forceinline__ float b2f(unsigned short u){
  union { unsigned u; float f; } c; c.u = ((unsigned)u) << 16; return c.f;
}
__device__ __forceinline__ unsigned short f2b(float f){
  union { float f; unsigned u; } c; c.f = f;
  unsigned r = c.u + 0x7fffu + ((c.u >> 16) & 1u);
  return (unsigned short)(r >> 16);
}
__device__ __forceinline__ int clampi(int v, int lo, int hi){
  return v < lo ? lo : (v > hi ? hi : v);
}
__device__ __forceinline__ void unpack8(uint4 v, float* o){
  o[0] = b2f((unsigned short)(v.x & 0xffff)); o[1] = b2f((unsigned short)(v.x >> 16));
  o[2] = b2f((unsigned short)(v.y & 0xffff)); o[3] = b2f((unsigned short)(v.y >> 16));
  o[4] = b2f((unsigned short)(v.z & 0xffff)); o[5] = b2f((unsigned short)(v.z >> 16));
  o[6] = b2f((unsigned short)(v.w & 0xffff)); o[7] = b2f((unsigned short)(v.w >> 16));
}
// 4 x fp8(e4m3, OCP on gfx950) packed in a dword -> 4 floats via v_cvt_pk_f32_fp8
__device__ __forceinline__ void cvt4(unsigned v, float* o){
  f32x2 lo = __builtin_amdgcn_cvt_pk_f32_fp8((int)v, false);
  f32x2 hi = __builtin_amdgcn_cvt_pk_f32_fp8((int)v, true);
  o[0] = lo.x; o[1] = lo.y; o[2] = hi.x; o[3] = hi.y;
}

// ---- K_pre: heterogeneous grid. Blocks [0,K1B): xw=x@W -> fp8 + a_src(fp16)
// + a_dst(fp32). Blocks [K1B,..): coarse 500-bin histogram of dst. ----
__global__ __launch_bounds__(256) void k_pre(
    const unsigned short* __restrict__ x, const unsigned short* __restrict__ W,
    const unsigned short* __restrict__ attS, const unsigned short* __restrict__ attD,
    const int* __restrict__ ei,
    unsigned char* __restrict__ xw8, __half* __restrict__ a_srch,
    float* __restrict__ a_dst, int* __restrict__ cc)
{
  __shared__ float Wsf[64 * 64];
  __shared__ float as_s[64];
  __shared__ float ad_s[64];
  __shared__ int hh[NBUCK];
  int t = threadIdx.x;

  if (blockIdx.x >= K1B) {
    // ---- coarse histogram part ----
    for (int i = t; i < NBUCK; i += 256) hh[i] = 0;
    __syncthreads();
    int g = (blockIdx.x - K1B) * 256 + t;
    if (g < N_EDGESC / 4) {
      int4 d = ((const int4*)(ei + N_EDGESC))[g];
      atomicAdd(&hh[clampi(d.x, 0, N_NODESC - 1) / BSZ], 1);
      atomicAdd(&hh[clampi(d.y, 0, N_NODESC - 1) / BSZ], 1);
      atomicAdd(&hh[clampi(d.z, 0, N_NODESC - 1) / BSZ], 1);
      atomicAdd(&hh[clampi(d.w, 0, N_NODESC - 1) / BSZ], 1);
    }
    __syncthreads();
    for (int i = t; i < NBUCK; i += 256) if (hh[i]) atomicAdd(&cc[i], hh[i]);
    return;
  }

  // ---- node transform part ----
  for (int i = t; i < 4096; i += 256) Wsf[i] = b2f(W[i]);
  if (t < 64) { as_s[t] = b2f(attS[t]); ad_s[t] = b2f(attD[t]); }
  __syncthreads();

  int g    = t & 3;
  int slot = t >> 2;
  int n0 = blockIdx.x * 256 + slot * 4;

  float acc[4][16];
  #pragma unroll
  for (int j = 0; j < 4; j++)
    #pragma unroll
    for (int c = 0; c < 16; c++) acc[j][c] = 0.f;

  const float4* Ws4 = (const float4*)Wsf;
  for (int i = 0; i < 8; i++) {
    float xu[4][8];
    #pragma unroll
    for (int j = 0; j < 4; j++) {
      int n = n0 + j;
      uint4 v = make_uint4(0u,0u,0u,0u);
      if (n < N_NODESC) v = ((const uint4*)(x + (size_t)n * 64))[i];
      unpack8(v, xu[j]);
    }
    #pragma unroll
    for (int u = 0; u < 8; u++) {
      int k = i * 8 + u;
      float4 w0 = Ws4[k * 16 + g * 4 + 0];
      float4 w1 = Ws4[k * 16 + g * 4 + 1];
      float4 w2 = Ws4[k * 16 + g * 4 + 2];
      float4 w3 = Ws4[k * 16 + g * 4 + 3];
      #pragma unroll
      for (int j = 0; j < 4; j++) {
        float xk = xu[j][u];
        acc[j][ 0] += xk * w0.x; acc[j][ 1] += xk * w0.y;
        acc[j][ 2] += xk * w0.z; acc[j][ 3] += xk * w0.w;
        acc[j][ 4] += xk * w1.x; acc[j][ 5] += xk * w1.y;
        acc[j][ 6] += xk * w1.z; acc[j][ 7] += xk * w1.w;
        acc[j][ 8] += xk * w2.x; acc[j][ 9] += xk * w2.y;
        acc[j][10] += xk * w2.z; acc[j][11] += xk * w2.w;
        acc[j][12] += xk * w3.x; acc[j][13] += xk * w3.y;
        acc[j][14] += xk * w3.z; acc[j][15] += xk * w3.w;
      }
    }
  }

  #pragma unroll
  for (int j = 0; j < 4; j++) {
    int n = n0 + j;
    if (n >= N_NODESC) break;
    union { unsigned u[4]; unsigned char b[16]; } pk;
    #pragma unroll
    for (int c = 0; c < 16; c++)
      pk.b[c] = (unsigned char)__hip_fp8_e4m3(acc[j][c]).__x;
    uint4 o; o.x = pk.u[0]; o.y = pk.u[1]; o.z = pk.u[2]; o.w = pk.u[3];
    *((uint4*)(xw8 + (size_t)n * 64 + g * 16)) = o;

    #pragma unroll
    for (int hl = 0; hl < 2; hl++) {
      int h = g * 2 + hl;
      float sa = 0.f, sd = 0.f;
      #pragma unroll
      for (int c = 0; c < 8; c++) {
        sa += acc[j][hl * 8 + c] * as_s[h * 8 + c];
        sd += acc[j][hl * 8 + c] * ad_s[h * 8 + c];
      }
      a_srch[n * 8 + h] = __float2half(sa);
      a_dst[n * 8 + h] = sd;
    }
  }
}

// ---- coarse scatter (1024 thr, 8192 edges/wg): self-scan of cc -> bstart,
// LDS counting-sort by bucket, contiguous run writes via zero-based gcur.
// Block 0 additionally publishes the exclusive bucket-prefix to boff[]. ----
__global__ __launch_bounds__(1024) void k_csort(const int* __restrict__ ei,
                                                const int* __restrict__ cc,
                                                int* __restrict__ gcur,
                                                unsigned* __restrict__ cs,
                                                int* __restrict__ boff) {
  __shared__ int bst[512];
  __shared__ int h[NBUCK], lst[NBUCK], lcur[NBUCK], gb[NBUCK];
  __shared__ int sc[512];
  __shared__ unsigned sorted[P3_EDGES];
  __shared__ unsigned short sbk[P3_EDGES];
  int t = threadIdx.x;
  int base = blockIdx.x * P3_EDGES;
  for (int i = t; i < NBUCK; i += 1024) h[i] = 0;
  int myc = 0;
  if (t < 512) { myc = (t < NBUCK) ? cc[t] : 0; bst[t] = myc; }
  __syncthreads();
  for (int off = 1; off < 512; off <<= 1) {
    int v = 0;
    if (t < 512) { v = bst[t]; if (t >= off) v += bst[t - off]; }
    __syncthreads();
    if (t < 512) bst[t] = v;
    __syncthreads();
  }
  if (blockIdx.x == 0 && t < NBUCK) boff[t] = bst[t] - myc;
  unsigned pk[8]; int bk[8];
  #pragma unroll
  for (int k = 0; k < 8; k++) {
    int idx = base + k * 1024 + t;
    bk[k] = -1;
    if (idx < N_EDGESC) {
      int s = clampi(ei[idx], 0, N_NODESC - 1);
      int d = clampi(ei[N_EDGESC + idx], 0, N_NODESC - 1);
      int b = d / BSZ;
      pk[k] = (unsigned)s | ((unsigned)(d - b * BSZ) << 17);
      bk[k] = b;
      atomicAdd(&h[b], 1);
    }
  }
  __syncthreads();
  if (t < 512) sc[t] = (t < NBUCK) ? h[t] : 0;
  __syncthreads();
  for (int off = 1; off < 512; off <<= 1) {
    int v = 0;
    if (t < 512) { v = sc[t]; if (t >= off) v += sc[t - off]; }
    __syncthreads();
    if (t < 512) sc[t] = v;
    __syncthreads();
  }
  if (t < NBUCK) {
    int ex = sc[t] - h[t];
    lst[t] = ex; lcur[t] = ex;
    if (h[t]) gb[t] = (bst[t] - myc) + atomicAdd(&gcur[t], h[t]);
  }
  __syncthreads();
  #pragma unroll
  for (int k = 0; k < 8; k++) if (bk[k] >= 0) {
    int p = atomicAdd(&lcur[bk[k]], 1);
    sorted[p] = pk[k];
    sbk[p] = (unsigned short)bk[k];
  }
  __syncthreads();
  int cnt = N_EDGESC - base; if (cnt > P3_EDGES) cnt = P3_EDGES;
  #pragma unroll
  for (int k = 0; k < 8; k++) {
    int i = k * 1024 + t;
    if (i < cnt) {
      int b = sbk[i];
      cs[gb[b] + (i - lst[b])] = sorted[i];
    }
  }
}

// ---- K_aggf v5c: TWO 512-thread WGs per bucket (100 dsts each), 1000 WGs.
// R1's fastest inner loop (dword gathers + ds_bpermute alpha broadcast,
// 1-deep pipeline). No launch_bounds min-waves hint: at ~30-50 VGPR the HW
// naturally resides 4 WGs/CU (32 waves); the hint was the only plausible
// compile-hazard in R4/R5's failed runs. Preamble: read boff/cc (no
// re-scan), filter-sort this half's edges into ssrc (CAPH=3072, mean 1600).
// All ssrc reads clamped to CAPH.
__global__ __launch_bounds__(512) void k_aggf(
    const __half* __restrict__ a_srch, const float* __restrict__ a_dst,
    const unsigned char* __restrict__ xw8, const unsigned* __restrict__ cs,
    const int* __restrict__ cc, const int* __restrict__ boff,
    const unsigned short* __restrict__ bias, unsigned short* __restrict__ nembh)
{
  __shared__ int lcnt[128], loff[128], lcur[128];
  __shared__ int ssrc[CAPH];
  int t = threadIdx.x;
  int b = blockIdx.x >> 1;
  int dlo = (blockIdx.x & 1) * HSZ;   // this WG's dst-range within the bucket
  int base = boff[b];
  int cnt  = cc[b];
  if (cnt > 12 * 512) cnt = 12 * 512;  // 6144 cap (astronomically safe)

  if (t < 128) lcnt[t] = 0;
  __syncthreads();

  // read the bucket's edges, keep those whose dl is in [dlo, dlo+HSZ)
  unsigned ce[12];
  #pragma unroll
  for (int j = 0; j < 12; j++) {
    int i = t + j * 512;
    ce[j] = 0xFFFFFFFFu;
    if (i < cnt) {
      unsigned e = cs[base + i];
      int dl = (int)(e >> 17);
      if (dl >= dlo && dl < dlo + HSZ) {
        ce[j] = e;
        atomicAdd(&lcnt[dl - dlo], 1);
      }
    }
  }
  __syncthreads();
  if (t < 128) loff[t] = lcnt[t];
  __syncthreads();
  for (int off = 1; off < 128; off <<= 1) {
    int v = 0;
    if (t < 128) { v = loff[t]; if (t >= off) v += loff[t - off]; }
    __syncthreads();
    if (t < 128) loff[t] = v;
    __syncthreads();
  }
  if (t < 128) { int ex = loff[t] - lcnt[t]; loff[t] = ex; lcur[t] = ex; }
  __syncthreads();
  #pragma unroll
  for (int j = 0; j < 12; j++) if (ce[j] != 0xFFFFFFFFu) {
    int p = atomicAdd(&lcur[(int)(ce[j] >> 17) - dlo], 1);
    if (p < CAPH) ssrc[p] = (int)(ce[j] & 0x1FFFFu);
  }
  __syncthreads();

  int wv = t >> 6;        // wave 0..7
  int l  = t & 63;
  int H  = l >> 3;        // edge offset within 8-group (w-producer role)
  int hw = l & 7;         // head (w-producer role)
  int k  = l & 15;        // channel quad: channels 4k..4k+3
  int g  = l >> 4;        // edge stripe (0..3)
  int h2 = k >> 1;        // head owning channels 4k..4k+3

  int bp0 = ((g << 3) | h2) << 2;          // bpermute addr: edge g, head h2
  int bp1 = (((g + 4) << 3) | h2) << 2;    // edge 4+g, head h2

  uint2 bb = ((const uint2*)bias)[k];
  float bs0 = b2f((unsigned short)(bb.x & 0xffff));
  float bs1 = b2f((unsigned short)(bb.x >> 16));
  float bs2 = b2f((unsigned short)(bb.y & 0xffff));
  float bs3 = b2f((unsigned short)(bb.y >> 16));

  for (int d2 = wv; d2 < HSZ; d2 += 8) {
    int dl  = dlo + d2;
    int dst = b * BSZ + dl;
    float adW = a_dst[dst * 8 + hw];                     // for edge alphas
    float adA = a_dst[dst * 8 + h2];                     // for self
    float zs  = __half2float(a_srch[dst * 8 + h2]) + adA;
    float selfw = __expf(fmaxf(zs, 0.2f * zs));

    unsigned sd = *(const unsigned*)(xw8 + (size_t)dst * 64 + (k << 2));
    float sx[4]; cvt4(sd, sx);
    float sw = (g == 0) ? selfw : 0.f;
    float a0 = sw * sx[0], a1 = sw * sx[1], a2 = sw * sx[2], a3 = sw * sx[3];

    int beg  = loff[d2];
    if (beg > CAPH) beg = CAPH;
    int deg  = lcnt[d2];
    int end2 = beg + deg;
    if (end2 > CAPH) end2 = CAPH;        // hardening: never read past ssrc
    deg = end2 - beg;
    float lw = 0.f;

    if (deg > 0) {
      int last = end2 - 1;
      // prologue: prefetch group 0
      int iw = beg + H; if (iw > last) iw = last;
      float av = __half2float(a_srch[ssrc[iw] * 8 + hw]);
      int e0 = beg + g;     if (e0 > last) e0 = last;
      int e1 = beg + 4 + g; if (e1 > last) e1 = last;
      unsigned d0 = *(const unsigned*)(xw8 + (size_t)ssrc[e0] * 64 + (k << 2));
      unsigned d1 = *(const unsigned*)(xw8 + (size_t)ssrc[e1] * 64 + (k << 2));

      for (int i = beg; i < end2; i += 8) {
        float z = av + adW;
        float w = __expf(fmaxf(z, 0.2f * z));
        w = (i + H < end2) ? w : 0.f;
        lw += w;
        unsigned c0 = d0, c1 = d1;
        int nx = i + 8;
        if (nx < end2) {
          int iw2 = nx + H; if (iw2 > last) iw2 = last;
          av = __half2float(a_srch[ssrc[iw2] * 8 + hw]);
          int f0 = nx + g;     if (f0 > last) f0 = last;
          int f1 = nx + 4 + g; if (f1 > last) f1 = last;
          d0 = *(const unsigned*)(xw8 + (size_t)ssrc[f0] * 64 + (k << 2));
          d1 = *(const unsigned*)(xw8 + (size_t)ssrc[f1] * 64 + (k << 2));
        }
        int wi = __float_as_int(w);
        float w0 = __int_as_float(__builtin_amdgcn_ds_bpermute(bp0, wi));
        float w1 = __int_as_float(__builtin_amdgcn_ds_bpermute(bp1, wi));
        float x0[4]; cvt4(c0, x0);
        a0 += w0 * x0[0]; a1 += w0 * x0[1]; a2 += w0 * x0[2]; a3 += w0 * x0[3];
        float x1[4]; cvt4(c1, x1);
        a0 += w1 * x1[0]; a1 += w1 * x1[1]; a2 += w1 * x1[2]; a3 += w1 * x1[3];
      }
    }

    // reduce partial sums across the 4 edge stripes
    a0 += __shfl_xor(a0, 16, 64); a0 += __shfl_xor(a0, 32, 64);
    a1 += __shfl_xor(a1, 16, 64); a1 += __shfl_xor(a1, 32, 64);
    a2 += __shfl_xor(a2, 16, 64); a2 += __shfl_xor(a2, 32, 64);
    a3 += __shfl_xor(a3, 16, 64); a3 += __shfl_xor(a3, 32, 64);
    lw += __shfl_xor(lw, 8, 64);
    lw += __shfl_xor(lw, 16, 64);
    lw += __shfl_xor(lw, 32, 64);
    float dsum = __shfl(lw, h2, 64);     // full per-head edge sum

    float denom = selfw + dsum;
    if (l < 16) {
      float inv = __builtin_amdgcn_rcpf(denom);
      float v0 = a0 * inv + bs0; v0 = v0 > 0.f ? v0 : 0.f;
      float v1 = a1 * inv + bs1; v1 = v1 > 0.f ? v1 : 0.f;
      float v2 = a2 * inv + bs2; v2 = v2 > 0.f ? v2 : 0.f;
      float v3 = a3 * inv + bs3; v3 = v3 > 0.f ? v3 : 0.f;
      uint2 o;
      o.x = (unsigned)f2b(v0) | ((unsigned)f2b(v1) << 16);
      o.y = (unsigned)f2b(v2) | ((unsigned)f2b(v3) << 16);
      ((uint2*)nembh)[(size_t)dst * 16 + k] = o;
    }
  }
}

// ---- K6: padded gather from bf16 nemb -> fp32 out + seq_lengths tail ----
__global__ __launch_bounds__(256) void k6_gather(
    const unsigned short* __restrict__ nembh, const int* __restrict__ traj,
    const int* __restrict__ lens, float* __restrict__ out)
{
  int gid = blockIdx.x * 256 + threadIdx.x;
  if (gid < BATCHC * MAXLENC * 16) {
    int b = gid >> 15;
    int rem = gid & 32767;
    int l = rem >> 4;
    int ch = rem & 15;
    int len = clampi(lens[b], 0, MAXLENC);
    float4 val = make_float4(0.f, 0.f, 0.f, 0.f);
    if (l < len) {
      int node = clampi(traj[b * MAXLENC + l], 0, N_NODESC - 1);
      uint2 q = ((const uint2*)nembh)[(size_t)node * 16 + ch];
      val = make_float4(b2f((unsigned short)(q.x & 0xffff)),
                        b2f((unsigned short)(q.x >> 16)),
                        b2f((unsigned short)(q.y & 0xffff)),
                        b2f((unsigned short)(q.y >> 16)));
    }
    ((float4*)out)[gid] = val;
  }
  if (gid < BATCHC) {
    out[(size_t)BATCHC * MAXLENC * FEATC + gid] = (float)lens[gid];
  }
}

extern "C" void kernel_launch(void* const* d_in, const int* in_sizes, int n_in,
                              void* d_out, int out_size, void* d_ws, size_t ws_size,
                              hipStream_t stream) {
  const unsigned short* x    = (const unsigned short*)d_in[0];
  const unsigned short* W    = (const unsigned short*)d_in[1];
  const unsigned short* attS = (const unsigned short*)d_in[2];
  const unsigned short* attD = (const unsigned short*)d_in[3];
  const unsigned short* bias = (const unsigned short*)d_in[4];
  const int* ei   = (const int*)d_in[5];
  const int* traj = (const int*)d_in[6];
  const int* lens = (const int*)d_in[7];
  float* out = (float*)d_out;

  // workspace (float units, max 9.9M floats = 39.6 MB; under proven size):
  //  [0, 1.6M)        xw fp8 (6.4M bytes)
  //  [3.2M, 3.6M)     a_src fp16 (800k half)
  //  [4.0M, 4.8M)     a_dst fp32
  //  [4.9M, +512)     ccounts (500)
  //  [+512, +1024)    gcur (500, zero-based)   -- one memset covers both
  //  [+1024, +1536)   boff (500, written by k_csort block 0)
  //  [5.0M, 6.6M)     cs (packed uint, 1.6M)
  //  [6.7M, 9.9M)     nemb bf16 (6.4M ushort)
  float* F = (float*)d_ws;
  unsigned char* xw8 = (unsigned char*)d_ws;
  __half* a_srch = (__half*)(F + 3200000);
  float* a_dst   = F + 4000000;
  int* ccounts   = (int*)(F + 4900000);
  int* gcur      = (int*)(F + 4900000) + 512;
  int* boff      = (int*)(F + 4900000) + 1024;
  unsigned* cs   = (unsigned*)(F + 5000000);
  unsigned short* nembh = (unsigned short*)(F + 6700000);

  hipMemsetAsync(ccounts, 0, 1024 * sizeof(int), stream);
  k_pre<<<K1B + (N_EDGESC / 4 + 255) / 256, 256, 0, stream>>>(
      x, W, attS, attD, ei, xw8, a_srch, a_dst, ccounts);
  k_csort<<<(N_EDGESC + P3_EDGES - 1) / P3_EDGES, 1024, 0, stream>>>(ei, ccounts, gcur, cs, boff);
  k_aggf<<<NBUCK * 2, 512, 0, stream>>>(a_srch, a_dst, xw8, cs, ccounts, boff, bias, nembh);
  k6_gather<<<(BATCHC * MAXLENC * 16 + 255) / 256, 256, 0, stream>>>(nembh, traj, lens, out);
}

// Round 7
// 191.328 us; speedup vs baseline: 3.9845x; 1.0495x over previous
//
#include <hip/hip_runtime.h>
#include <hip/hip_bf16.h>
#include <hip/hip_fp8.h>
#include <hip/hip_fp16.h>

#define N_NODESC 100000
#define N_EDGESC 1600000
#define FEATC 64
#define HEADSC 8
#define BATCHC 64
#define MAXLENC 2048
#define NBUCK 500          // 500 buckets x exactly 200 dst nodes
#define BSZ 200
#define HSZ 100            // dsts per k_aggf workgroup (half bucket)
#define CAPH 3072          // LDS edge capacity per half-bucket (mean 1600, sigma ~40)
#define P3_EDGES 8192      // edges per k_csort workgroup (1024 thr x 8)
#define K1B 391            // k_pre blocks doing the node transform

typedef float f32x2 __attribute__((ext_vector_type(2)));

__device__ __forceinline__ float b2f(unsigned short u){
  union { unsigned u; float f; } c; c.u = ((unsigned)u) << 16; return c.f;
}
__device__ __forceinline__ unsigned short f2b(float f){
  union { float f; unsigned u; } c; c.f = f;
  unsigned r = c.u + 0x7fffu + ((c.u >> 16) & 1u);
  return (unsigned short)(r >> 16);
}
__device__ __forceinline__ int clampi(int v, int lo, int hi){
  return v < lo ? lo : (v > hi ? hi : v);
}
__device__ __forceinline__ void unpack8(uint4 v, float* o){
  o[0] = b2f((unsigned short)(v.x & 0xffff)); o[1] = b2f((unsigned short)(v.x >> 16));
  o[2] = b2f((unsigned short)(v.y & 0xffff)); o[3] = b2f((unsigned short)(v.y >> 16));
  o[4] = b2f((unsigned short)(v.z & 0xffff)); o[5] = b2f((unsigned short)(v.z >> 16));
  o[6] = b2f((unsigned short)(v.w & 0xffff)); o[7] = b2f((unsigned short)(v.w >> 16));
}
// 4 x fp8(e4m3, OCP on gfx950) packed in a dword -> 4 floats via v_cvt_pk_f32_fp8
__device__ __forceinline__ void cvt4(unsigned v, float* o){
  f32x2 lo = __builtin_amdgcn_cvt_pk_f32_fp8((int)v, false);
  f32x2 hi = __builtin_amdgcn_cvt_pk_f32_fp8((int)v, true);
  o[0] = lo.x; o[1] = lo.y; o[2] = hi.x; o[3] = hi.y;
}

// ---- K_pre: heterogeneous grid. Blocks [0,K1B): xw=x@W -> fp8 + a_src(fp16)
// + a_dst(fp32). Blocks [K1B,..): coarse 500-bin histogram of dst. ----
__global__ __launch_bounds__(256) void k_pre(
    const unsigned short* __restrict__ x, const unsigned short* __restrict__ W,
    const unsigned short* __restrict__ attS, const unsigned short* __restrict__ attD,
    const int* __restrict__ ei,
    unsigned char* __restrict__ xw8, __half* __restrict__ a_srch,
    float* __restrict__ a_dst, int* __restrict__ cc)
{
  __shared__ float Wsf[64 * 64];
  __shared__ float as_s[64];
  __shared__ float ad_s[64];
  __shared__ int hh[NBUCK];
  int t = threadIdx.x;

  if (blockIdx.x >= K1B) {
    // ---- coarse histogram part ----
    for (int i = t; i < NBUCK; i += 256) hh[i] = 0;
    __syncthreads();
    int g = (blockIdx.x - K1B) * 256 + t;
    if (g < N_EDGESC / 4) {
      int4 d = ((const int4*)(ei + N_EDGESC))[g];
      atomicAdd(&hh[clampi(d.x, 0, N_NODESC - 1) / BSZ], 1);
      atomicAdd(&hh[clampi(d.y, 0, N_NODESC - 1) / BSZ], 1);
      atomicAdd(&hh[clampi(d.z, 0, N_NODESC - 1) / BSZ], 1);
      atomicAdd(&hh[clampi(d.w, 0, N_NODESC - 1) / BSZ], 1);
    }
    __syncthreads();
    for (int i = t; i < NBUCK; i += 256) if (hh[i]) atomicAdd(&cc[i], hh[i]);
    return;
  }

  // ---- node transform part ----
  for (int i = t; i < 4096; i += 256) Wsf[i] = b2f(W[i]);
  if (t < 64) { as_s[t] = b2f(attS[t]); ad_s[t] = b2f(attD[t]); }
  __syncthreads();

  int g    = t & 3;
  int slot = t >> 2;
  int n0 = blockIdx.x * 256 + slot * 4;

  float acc[4][16];
  #pragma unroll
  for (int j = 0; j < 4; j++)
    #pragma unroll
    for (int c = 0; c < 16; c++) acc[j][c] = 0.f;

  const float4* Ws4 = (const float4*)Wsf;
  for (int i = 0; i < 8; i++) {
    float xu[4][8];
    #pragma unroll
    for (int j = 0; j < 4; j++) {
      int n = n0 + j;
      uint4 v = make_uint4(0u,0u,0u,0u);
      if (n < N_NODESC) v = ((const uint4*)(x + (size_t)n * 64))[i];
      unpack8(v, xu[j]);
    }
    #pragma unroll
    for (int u = 0; u < 8; u++) {
      int k = i * 8 + u;
      float4 w0 = Ws4[k * 16 + g * 4 + 0];
      float4 w1 = Ws4[k * 16 + g * 4 + 1];
      float4 w2 = Ws4[k * 16 + g * 4 + 2];
      float4 w3 = Ws4[k * 16 + g * 4 + 3];
      #pragma unroll
      for (int j = 0; j < 4; j++) {
        float xk = xu[j][u];
        acc[j][ 0] += xk * w0.x; acc[j][ 1] += xk * w0.y;
        acc[j][ 2] += xk * w0.z; acc[j][ 3] += xk * w0.w;
        acc[j][ 4] += xk * w1.x; acc[j][ 5] += xk * w1.y;
        acc[j][ 6] += xk * w1.z; acc[j][ 7] += xk * w1.w;
        acc[j][ 8] += xk * w2.x; acc[j][ 9] += xk * w2.y;
        acc[j][10] += xk * w2.z; acc[j][11] += xk * w2.w;
        acc[j][12] += xk * w3.x; acc[j][13] += xk * w3.y;
        acc[j][14] += xk * w3.z; acc[j][15] += xk * w3.w;
      }
    }
  }

  #pragma unroll
  for (int j = 0; j < 4; j++) {
    int n = n0 + j;
    if (n >= N_NODESC) break;
    union { unsigned u[4]; unsigned char b[16]; } pk;
    #pragma unroll
    for (int c = 0; c < 16; c++)
      pk.b[c] = (unsigned char)__hip_fp8_e4m3(acc[j][c]).__x;
    uint4 o; o.x = pk.u[0]; o.y = pk.u[1]; o.z = pk.u[2]; o.w = pk.u[3];
    *((uint4*)(xw8 + (size_t)n * 64 + g * 16)) = o;

    #pragma unroll
    for (int hl = 0; hl < 2; hl++) {
      int h = g * 2 + hl;
      float sa = 0.f, sd = 0.f;
      #pragma unroll
      for (int c = 0; c < 8; c++) {
        sa += acc[j][hl * 8 + c] * as_s[h * 8 + c];
        sd += acc[j][hl * 8 + c] * ad_s[h * 8 + c];
      }
      a_srch[n * 8 + h] = __float2half(sa);
      a_dst[n * 8 + h] = sd;
    }
  }
}

// ---- coarse scatter (1024 thr, 8192 edges/wg): self-scan of cc -> bstart,
// LDS counting-sort by bucket, contiguous run writes via zero-based gcur.
// Block 0 additionally publishes the exclusive bucket-prefix to boff[]. ----
__global__ __launch_bounds__(1024) void k_csort(const int* __restrict__ ei,
                                                const int* __restrict__ cc,
                                                int* __restrict__ gcur,
                                                unsigned* __restrict__ cs,
                                                int* __restrict__ boff) {
  __shared__ int bst[512];
  __shared__ int h[NBUCK], lst[NBUCK], lcur[NBUCK], gb[NBUCK];
  __shared__ int sc[512];
  __shared__ unsigned sorted[P3_EDGES];
  __shared__ unsigned short sbk[P3_EDGES];
  int t = threadIdx.x;
  int base = blockIdx.x * P3_EDGES;
  for (int i = t; i < NBUCK; i += 1024) h[i] = 0;
  int myc = 0;
  if (t < 512) { myc = (t < NBUCK) ? cc[t] : 0; bst[t] = myc; }
  __syncthreads();
  for (int off = 1; off < 512; off <<= 1) {
    int v = 0;
    if (t < 512) { v = bst[t]; if (t >= off) v += bst[t - off]; }
    __syncthreads();
    if (t < 512) bst[t] = v;
    __syncthreads();
  }
  if (blockIdx.x == 0 && t < NBUCK) boff[t] = bst[t] - myc;
  unsigned pk[8]; int bk[8];
  #pragma unroll
  for (int k = 0; k < 8; k++) {
    int idx = base + k * 1024 + t;
    bk[k] = -1;
    if (idx < N_EDGESC) {
      int s = clampi(ei[idx], 0, N_NODESC - 1);
      int d = clampi(ei[N_EDGESC + idx], 0, N_NODESC - 1);
      int b = d / BSZ;
      pk[k] = (unsigned)s | ((unsigned)(d - b * BSZ) << 17);
      bk[k] = b;
      atomicAdd(&h[b], 1);
    }
  }
  __syncthreads();
  if (t < 512) sc[t] = (t < NBUCK) ? h[t] : 0;
  __syncthreads();
  for (int off = 1; off < 512; off <<= 1) {
    int v = 0;
    if (t < 512) { v = sc[t]; if (t >= off) v += sc[t - off]; }
    __syncthreads();
    if (t < 512) sc[t] = v;
    __syncthreads();
  }
  if (t < NBUCK) {
    int ex = sc[t] - h[t];
    lst[t] = ex; lcur[t] = ex;
    if (h[t]) gb[t] = (bst[t] - myc) + atomicAdd(&gcur[t], h[t]);
  }
  __syncthreads();
  #pragma unroll
  for (int k = 0; k < 8; k++) if (bk[k] >= 0) {
    int p = atomicAdd(&lcur[bk[k]], 1);
    sorted[p] = pk[k];
    sbk[p] = (unsigned short)bk[k];
  }
  __syncthreads();
  int cnt = N_EDGESC - base; if (cnt > P3_EDGES) cnt = P3_EDGES;
  #pragma unroll
  for (int k = 0; k < 8; k++) {
    int i = k * 1024 + t;
    if (i < cnt) {
      int b = sbk[i];
      cs[gb[b] + (i - lst[b])] = sorted[i];
    }
  }
}

// ---- K_aggf v6: TWO 512-thread WGs per bucket (100 dsts each), 1000 WGs.
// FOUR lanes own one dst: lane = (dst-slot s=l>>2, quad q=l&3). Quad q covers
// channels 16q..16q+15 = heads 2q,2q+1, so each lane computes its own two
// edge weights -> ZERO cross-lane ops anywhere (no shuffles, no bpermute;
// denominators lane-local). Per edge per lane: one uint4 xw8 load (4 lanes =
// full 64B row) + one half2 a_src load; edge indices come from LDS, so an
// explicit 2-deep rotation keeps 4 loads in flight with no dependent chain.
// d2 = s*8 + wv balances the 100 dsts across the 8 waves (~12.5 each).
__global__ __launch_bounds__(512) void k_aggf(
    const __half* __restrict__ a_srch, const float* __restrict__ a_dst,
    const unsigned char* __restrict__ xw8, const unsigned* __restrict__ cs,
    const int* __restrict__ cc, const int* __restrict__ boff,
    const unsigned short* __restrict__ bias, unsigned short* __restrict__ nembh)
{
  __shared__ int lcnt[128], loff[128], lcur[128];
  __shared__ int ssrc[CAPH];
  int t = threadIdx.x;
  int b = blockIdx.x >> 1;
  int dlo = (blockIdx.x & 1) * HSZ;   // this WG's dst-range within the bucket
  int base = boff[b];
  int cnt  = cc[b];
  if (cnt > 12 * 512) cnt = 12 * 512;  // 6144 cap (astronomically safe)

  if (t < 128) lcnt[t] = 0;
  __syncthreads();

  // read the bucket's edges, keep those whose dl is in [dlo, dlo+HSZ)
  unsigned ce[12];
  #pragma unroll
  for (int j = 0; j < 12; j++) {
    int i = t + j * 512;
    ce[j] = 0xFFFFFFFFu;
    if (i < cnt) {
      unsigned e = cs[base + i];
      int dl = (int)(e >> 17);
      if (dl >= dlo && dl < dlo + HSZ) {
        ce[j] = e;
        atomicAdd(&lcnt[dl - dlo], 1);
      }
    }
  }
  __syncthreads();
  if (t < 128) loff[t] = lcnt[t];
  __syncthreads();
  for (int off = 1; off < 128; off <<= 1) {
    int v = 0;
    if (t < 128) { v = loff[t]; if (t >= off) v += loff[t - off]; }
    __syncthreads();
    if (t < 128) loff[t] = v;
    __syncthreads();
  }
  if (t < 128) { int ex = loff[t] - lcnt[t]; loff[t] = ex; lcur[t] = ex; }
  __syncthreads();
  #pragma unroll
  for (int j = 0; j < 12; j++) if (ce[j] != 0xFFFFFFFFu) {
    int p = atomicAdd(&lcur[(int)(ce[j] >> 17) - dlo], 1);
    if (p < CAPH) ssrc[p] = (int)(ce[j] & 0x1FFFFu);
  }
  __syncthreads();

  int wv = t >> 6;        // wave 0..7
  int l  = t & 63;
  int s  = l >> 2;        // dst slot within wave (0..15)
  int q  = l & 3;         // channel quad: channels 16q..16q+15, heads 2q,2q+1
  int d2 = s * 8 + wv;    // 0..127, balanced across waves

  if (d2 < HSZ) {
    int dst = b * BSZ + dlo + d2;

    // self weights for heads 2q, 2q+1
    float2 sa2 = __half22float2(*(const __half2*)(a_srch + dst * 8 + q * 2));
    float2 ad2 = *(const float2*)(a_dst + dst * 8 + q * 2);
    float z0 = sa2.x + ad2.x, z1 = sa2.y + ad2.y;
    float den0 = __expf(fmaxf(z0, 0.2f * z0));
    float den1 = __expf(fmaxf(z1, 0.2f * z1));

    // acc init = selfw * x_self (16 channels)
    uint4 xs = *(const uint4*)(xw8 + (size_t)dst * 64 + q * 16);
    float xv[16];
    cvt4(xs.x, xv); cvt4(xs.y, xv + 4); cvt4(xs.z, xv + 8); cvt4(xs.w, xv + 12);
    float acc[16];
    #pragma unroll
    for (int c = 0; c < 8; c++) { acc[c] = den0 * xv[c]; acc[8 + c] = den1 * xv[8 + c]; }

    int beg = loff[d2]; if (beg > CAPH) beg = CAPH;
    int end2 = beg + lcnt[d2]; if (end2 > CAPH) end2 = CAPH;

    // 2-deep rotation: indices from LDS, loads independent
    int nA = (beg < end2) ? ssrc[beg] : 0;
    int nB = (beg + 1 < end2) ? ssrc[beg + 1] : 0;
    __half2 aA = *(const __half2*)(a_srch + nA * 8 + q * 2);
    uint4   xA = *(const uint4*)(xw8 + (size_t)nA * 64 + q * 16);
    __half2 aB = *(const __half2*)(a_srch + nB * 8 + q * 2);
    uint4   xB = *(const uint4*)(xw8 + (size_t)nB * 64 + q * 16);

    for (int i = beg; i < end2; i++) {
      float2 af = __half22float2(aA);
      uint4  xc = xA;
      aA = aB; xA = xB;
      int nn = (i + 2 < end2) ? ssrc[i + 2] : 0;
      aB = *(const __half2*)(a_srch + nn * 8 + q * 2);
      xB = *(const uint4*)(xw8 + (size_t)nn * 64 + q * 16);

      float e0 = af.x + ad2.x, e1 = af.y + ad2.y;
      float w0 = __expf(fmaxf(e0, 0.2f * e0));
      float w1 = __expf(fmaxf(e1, 0.2f * e1));
      den0 += w0; den1 += w1;
      float yv[16];
      cvt4(xc.x, yv); cvt4(xc.y, yv + 4); cvt4(xc.z, yv + 8); cvt4(xc.w, yv + 12);
      #pragma unroll
      for (int c = 0; c < 8; c++) { acc[c] += w0 * yv[c]; acc[8 + c] += w1 * yv[8 + c]; }
    }

    // epilogue: divide, bias, relu, pack 16 bf16 = 32B
    float inv0 = __builtin_amdgcn_rcpf(den0);
    float inv1 = __builtin_amdgcn_rcpf(den1);
    uint4 bb0 = ((const uint4*)bias)[q * 2];
    uint4 bb1 = ((const uint4*)bias)[q * 2 + 1];
    unsigned bw[8] = {bb0.x, bb0.y, bb0.z, bb0.w, bb1.x, bb1.y, bb1.z, bb1.w};
    unsigned ow[8];
    #pragma unroll
    for (int p = 0; p < 8; p++) {
      float inv = (p < 4) ? inv0 : inv1;
      float v0 = acc[p * 2]     * inv + b2f((unsigned short)(bw[p] & 0xffff));
      float v1 = acc[p * 2 + 1] * inv + b2f((unsigned short)(bw[p] >> 16));
      v0 = fmaxf(v0, 0.f); v1 = fmaxf(v1, 0.f);
      ow[p] = (unsigned)f2b(v0) | ((unsigned)f2b(v1) << 16);
    }
    uint4 o0 = make_uint4(ow[0], ow[1], ow[2], ow[3]);
    uint4 o1 = make_uint4(ow[4], ow[5], ow[6], ow[7]);
    ((uint4*)nembh)[(size_t)dst * 8 + q * 2]     = o0;
    ((uint4*)nembh)[(size_t)dst * 8 + q * 2 + 1] = o1;
  }
}

// ---- K6: padded gather from bf16 nemb -> fp32 out + seq_lengths tail ----
__global__ __launch_bounds__(256) void k6_gather(
    const unsigned short* __restrict__ nembh, const int* __restrict__ traj,
    const int* __restrict__ lens, float* __restrict__ out)
{
  int gid = blockIdx.x * 256 + threadIdx.x;
  if (gid < BATCHC * MAXLENC * 16) {
    int b = gid >> 15;
    int rem = gid & 32767;
    int l = rem >> 4;
    int ch = rem & 15;
    int len = clampi(lens[b], 0, MAXLENC);
    float4 val = make_float4(0.f, 0.f, 0.f, 0.f);
    if (l < len) {
      int node = clampi(traj[b * MAXLENC + l], 0, N_NODESC - 1);
      uint2 q = ((const uint2*)nembh)[(size_t)node * 16 + ch];
      val = make_float4(b2f((unsigned short)(q.x & 0xffff)),
                        b2f((unsigned short)(q.x >> 16)),
                        b2f((unsigned short)(q.y & 0xffff)),
                        b2f((unsigned short)(q.y >> 16)));
    }
    ((float4*)out)[gid] = val;
  }
  if (gid < BATCHC) {
    out[(size_t)BATCHC * MAXLENC * FEATC + gid] = (float)lens[gid];
  }
}

extern "C" void kernel_launch(void* const* d_in, const int* in_sizes, int n_in,
                              void* d_out, int out_size, void* d_ws, size_t ws_size,
                              hipStream_t stream) {
  const unsigned short* x    = (const unsigned short*)d_in[0];
  const unsigned short* W    = (const unsigned short*)d_in[1];
  const unsigned short* attS = (const unsigned short*)d_in[2];
  const unsigned short* attD = (const unsigned short*)d_in[3];
  const unsigned short* bias = (const unsigned short*)d_in[4];
  const int* ei   = (const int*)d_in[5];
  const int* traj = (const int*)d_in[6];
  const int* lens = (const int*)d_in[7];
  float* out = (float*)d_out;

  // workspace (float units, max 9.9M floats = 39.6 MB; under proven size):
  //  [0, 1.6M)        xw fp8 (6.4M bytes)
  //  [3.2M, 3.6M)     a_src fp16 (800k half)
  //  [4.0M, 4.8M)     a_dst fp32
  //  [4.9M, +512)     ccounts (500)
  //  [+512, +1024)    gcur (500, zero-based)   -- one memset covers both
  //  [+1024, +1536)   boff (500, written by k_csort block 0)
  //  [5.0M, 6.6M)     cs (packed uint, 1.6M)
  //  [6.7M, 9.9M)     nemb bf16 (6.4M ushort)
  float* F = (float*)d_ws;
  unsigned char* xw8 = (unsigned char*)d_ws;
  __half* a_srch = (__half*)(F + 3200000);
  float* a_dst   = F + 4000000;
  int* ccounts   = (int*)(F + 4900000);
  int* gcur      = (int*)(F + 4900000) + 512;
  int* boff      = (int*)(F + 4900000) + 1024;
  unsigned* cs   = (unsigned*)(F + 5000000);
  unsigned short* nembh = (unsigned short*)(F + 6700000);

  hipMemsetAsync(ccounts, 0, 1024 * sizeof(int), stream);
  k_pre<<<K1B + (N_EDGESC / 4 + 255) / 256, 256, 0, stream>>>(
      x, W, attS, attD, ei, xw8, a_srch, a_dst, ccounts);
  k_csort<<<(N_EDGESC + P3_EDGES - 1) / P3_EDGES, 1024, 0, stream>>>(ei, ccounts, gcur, cs, boff);
  k_aggf<<<NBUCK * 2, 512, 0, stream>>>(a_srch, a_dst, xw8, cs, ccounts, boff, bias, nembh);
  k6_gather<<<(BATCHC * MAXLENC * 16 + 255) / 256, 256, 0, stream>>>(nembh, traj, lens, out);
}

// Round 8
// 184.378 us; speedup vs baseline: 4.1347x; 1.0377x over previous
//
#include <hip/hip_runtime.h>
#include <hip/hip_bf16.h>
#include <hip/hip_fp8.h>
#include <hip/hip_fp16.h>

#define N_NODESC 100000
#define N_EDGESC 1600000
#define FEATC 64
#define HEADSC 8
#define BATCHC 64
#define MAXLENC 2048
#define NBUCK 500          // 500 buckets x exactly 200 dst nodes
#define BSZ 200
#define HSZ 100            // dsts per k_aggf workgroup (half bucket)
#define CAPH 3072          // LDS edge capacity per half-bucket (mean 1600, sigma ~40)
#define P3_EDGES 8192      // edges per k_csort workgroup (1024 thr x 8)
#define K1B 782            // k_pre blocks doing the node transform (128 nodes each)

typedef float f32x2 __attribute__((ext_vector_type(2)));

__device__ __forceinline__ float b2f(unsigned short u){
  union { unsigned u; float f; } c; c.u = ((unsigned)u) << 16; return c.f;
}
__device__ __forceinline__ unsigned short f2b(float f){
  union { float f; unsigned u; } c; c.f = f;
  unsigned r = c.u + 0x7fffu + ((c.u >> 16) & 1u);
  return (unsigned short)(r >> 16);
}
__device__ __forceinline__ int clampi(int v, int lo, int hi){
  return v < lo ? lo : (v > hi ? hi : v);
}
__device__ __forceinline__ void unpack8(uint4 v, float* o){
  o[0] = b2f((unsigned short)(v.x & 0xffff)); o[1] = b2f((unsigned short)(v.x >> 16));
  o[2] = b2f((unsigned short)(v.y & 0xffff)); o[3] = b2f((unsigned short)(v.y >> 16));
  o[4] = b2f((unsigned short)(v.z & 0xffff)); o[5] = b2f((unsigned short)(v.z >> 16));
  o[6] = b2f((unsigned short)(v.w & 0xffff)); o[7] = b2f((unsigned short)(v.w >> 16));
}
// 4 x fp8(e4m3, OCP on gfx950) packed in a dword -> 4 floats via v_cvt_pk_f32_fp8
__device__ __forceinline__ void cvt4(unsigned v, float* o){
  f32x2 lo = __builtin_amdgcn_cvt_pk_f32_fp8((int)v, false);
  f32x2 hi = __builtin_amdgcn_cvt_pk_f32_fp8((int)v, true);
  o[0] = lo.x; o[1] = lo.y; o[2] = hi.x; o[3] = hi.y;
}

// ---- K_pre v2: heterogeneous grid. Blocks [0,K1B): xw=x@W -> fp8 + a_src
// (fp16) + a_dst(fp32), 128 nodes/block, 2 nodes/thread (was 256/4: only
// 1.5 waves/SIMD of heavy work -> 17.7% occupancy, latency-serialized).
// 782 blocks = 3.1 waves/SIMD; LDS W reads still amortized over 2 nodes.
// Blocks [K1B,..): coarse 500-bin histogram of dst. ----
__global__ __launch_bounds__(256) void k_pre(
    const unsigned short* __restrict__ x, const unsigned short* __restrict__ W,
    const unsigned short* __restrict__ attS, const unsigned short* __restrict__ attD,
    const int* __restrict__ ei,
    unsigned char* __restrict__ xw8, __half* __restrict__ a_srch,
    float* __restrict__ a_dst, int* __restrict__ cc)
{
  __shared__ float Wsf[64 * 64];
  __shared__ float as_s[64];
  __shared__ float ad_s[64];
  __shared__ int hh[NBUCK];
  int t = threadIdx.x;

  if (blockIdx.x >= K1B) {
    // ---- coarse histogram part ----
    for (int i = t; i < NBUCK; i += 256) hh[i] = 0;
    __syncthreads();
    int g = (blockIdx.x - K1B) * 256 + t;
    if (g < N_EDGESC / 4) {
      int4 d = ((const int4*)(ei + N_EDGESC))[g];
      atomicAdd(&hh[clampi(d.x, 0, N_NODESC - 1) / BSZ], 1);
      atomicAdd(&hh[clampi(d.y, 0, N_NODESC - 1) / BSZ], 1);
      atomicAdd(&hh[clampi(d.z, 0, N_NODESC - 1) / BSZ], 1);
      atomicAdd(&hh[clampi(d.w, 0, N_NODESC - 1) / BSZ], 1);
    }
    __syncthreads();
    for (int i = t; i < NBUCK; i += 256) if (hh[i]) atomicAdd(&cc[i], hh[i]);
    return;
  }

  // ---- node transform part ----
  for (int i = t; i < 4096; i += 256) Wsf[i] = b2f(W[i]);
  if (t < 64) { as_s[t] = b2f(attS[t]); ad_s[t] = b2f(attD[t]); }
  __syncthreads();

  int g    = t & 3;
  int slot = t >> 2;
  int n0 = blockIdx.x * 128 + slot * 2;

  float acc[2][16];
  #pragma unroll
  for (int j = 0; j < 2; j++)
    #pragma unroll
    for (int c = 0; c < 16; c++) acc[j][c] = 0.f;

  const float4* Ws4 = (const float4*)Wsf;
  for (int i = 0; i < 8; i++) {
    float xu[2][8];
    #pragma unroll
    for (int j = 0; j < 2; j++) {
      int n = n0 + j;
      uint4 v = make_uint4(0u,0u,0u,0u);
      if (n < N_NODESC) v = ((const uint4*)(x + (size_t)n * 64))[i];
      unpack8(v, xu[j]);
    }
    #pragma unroll
    for (int u = 0; u < 8; u++) {
      int k = i * 8 + u;
      float4 w0 = Ws4[k * 16 + g * 4 + 0];
      float4 w1 = Ws4[k * 16 + g * 4 + 1];
      float4 w2 = Ws4[k * 16 + g * 4 + 2];
      float4 w3 = Ws4[k * 16 + g * 4 + 3];
      #pragma unroll
      for (int j = 0; j < 2; j++) {
        float xk = xu[j][u];
        acc[j][ 0] += xk * w0.x; acc[j][ 1] += xk * w0.y;
        acc[j][ 2] += xk * w0.z; acc[j][ 3] += xk * w0.w;
        acc[j][ 4] += xk * w1.x; acc[j][ 5] += xk * w1.y;
        acc[j][ 6] += xk * w1.z; acc[j][ 7] += xk * w1.w;
        acc[j][ 8] += xk * w2.x; acc[j][ 9] += xk * w2.y;
        acc[j][10] += xk * w2.z; acc[j][11] += xk * w2.w;
        acc[j][12] += xk * w3.x; acc[j][13] += xk * w3.y;
        acc[j][14] += xk * w3.z; acc[j][15] += xk * w3.w;
      }
    }
  }

  #pragma unroll
  for (int j = 0; j < 2; j++) {
    int n = n0 + j;
    if (n >= N_NODESC) break;
    union { unsigned u[4]; unsigned char b[16]; } pk;
    #pragma unroll
    for (int c = 0; c < 16; c++)
      pk.b[c] = (unsigned char)__hip_fp8_e4m3(acc[j][c]).__x;
    uint4 o; o.x = pk.u[0]; o.y = pk.u[1]; o.z = pk.u[2]; o.w = pk.u[3];
    *((uint4*)(xw8 + (size_t)n * 64 + g * 16)) = o;

    #pragma unroll
    for (int hl = 0; hl < 2; hl++) {
      int h = g * 2 + hl;
      float sa = 0.f, sd = 0.f;
      #pragma unroll
      for (int c = 0; c < 8; c++) {
        sa += acc[j][hl * 8 + c] * as_s[h * 8 + c];
        sd += acc[j][hl * 8 + c] * ad_s[h * 8 + c];
      }
      a_srch[n * 8 + h] = __float2half(sa);
      a_dst[n * 8 + h] = sd;
    }
  }
}

// ---- coarse scatter (1024 thr, 8192 edges/wg): self-scan of cc -> bstart,
// LDS counting-sort by bucket, contiguous run writes via zero-based gcur.
// Block 0 additionally publishes the exclusive bucket-prefix to boff[]. ----
__global__ __launch_bounds__(1024) void k_csort(const int* __restrict__ ei,
                                                const int* __restrict__ cc,
                                                int* __restrict__ gcur,
                                                unsigned* __restrict__ cs,
                                                int* __restrict__ boff) {
  __shared__ int bst[512];
  __shared__ int h[NBUCK], lst[NBUCK], lcur[NBUCK], gb[NBUCK];
  __shared__ int sc[512];
  __shared__ unsigned sorted[P3_EDGES];
  __shared__ unsigned short sbk[P3_EDGES];
  int t = threadIdx.x;
  int base = blockIdx.x * P3_EDGES;
  for (int i = t; i < NBUCK; i += 1024) h[i] = 0;
  int myc = 0;
  if (t < 512) { myc = (t < NBUCK) ? cc[t] : 0; bst[t] = myc; }
  __syncthreads();
  for (int off = 1; off < 512; off <<= 1) {
    int v = 0;
    if (t < 512) { v = bst[t]; if (t >= off) v += bst[t - off]; }
    __syncthreads();
    if (t < 512) bst[t] = v;
    __syncthreads();
  }
  if (blockIdx.x == 0 && t < NBUCK) boff[t] = bst[t] - myc;
  unsigned pk[8]; int bk[8];
  #pragma unroll
  for (int k = 0; k < 8; k++) {
    int idx = base + k * 1024 + t;
    bk[k] = -1;
    if (idx < N_EDGESC) {
      int s = clampi(ei[idx], 0, N_NODESC - 1);
      int d = clampi(ei[N_EDGESC + idx], 0, N_NODESC - 1);
      int b = d / BSZ;
      pk[k] = (unsigned)s | ((unsigned)(d - b * BSZ) << 17);
      bk[k] = b;
      atomicAdd(&h[b], 1);
    }
  }
  __syncthreads();
  if (t < 512) sc[t] = (t < NBUCK) ? h[t] : 0;
  __syncthreads();
  for (int off = 1; off < 512; off <<= 1) {
    int v = 0;
    if (t < 512) { v = sc[t]; if (t >= off) v += sc[t - off]; }
    __syncthreads();
    if (t < 512) sc[t] = v;
    __syncthreads();
  }
  if (t < NBUCK) {
    int ex = sc[t] - h[t];
    lst[t] = ex; lcur[t] = ex;
    if (h[t]) gb[t] = (bst[t] - myc) + atomicAdd(&gcur[t], h[t]);
  }
  __syncthreads();
  #pragma unroll
  for (int k = 0; k < 8; k++) if (bk[k] >= 0) {
    int p = atomicAdd(&lcur[bk[k]], 1);
    sorted[p] = pk[k];
    sbk[p] = (unsigned short)bk[k];
  }
  __syncthreads();
  int cnt = N_EDGESC - base; if (cnt > P3_EDGES) cnt = P3_EDGES;
  #pragma unroll
  for (int k = 0; k < 8; k++) {
    int i = k * 1024 + t;
    if (i < cnt) {
      int b = sbk[i];
      cs[gb[b] + (i - lst[b])] = sorted[i];
    }
  }
}

// ---- K_aggf v6: TWO 512-thread WGs per bucket (100 dsts each), 1000 WGs.
// FOUR lanes own one dst: lane = (dst-slot s=l>>2, quad q=l&3). Quad q covers
// channels 16q..16q+15 = heads 2q,2q+1, so each lane computes its own two
// edge weights -> ZERO cross-lane ops anywhere (no shuffles, no bpermute;
// denominators lane-local). Per edge per lane: one uint4 xw8 load (4 lanes =
// full 64B row) + one half2 a_src load; edge indices come from LDS, so an
// explicit 2-deep rotation keeps 4 loads in flight with no dependent chain.
// d2 = s*8 + wv balances the 100 dsts across the 8 waves (~12.5 each).
__global__ __launch_bounds__(512) void k_aggf(
    const __half* __restrict__ a_srch, const float* __restrict__ a_dst,
    const unsigned char* __restrict__ xw8, const unsigned* __restrict__ cs,
    const int* __restrict__ cc, const int* __restrict__ boff,
    const unsigned short* __restrict__ bias, unsigned short* __restrict__ nembh)
{
  __shared__ int lcnt[128], loff[128], lcur[128];
  __shared__ int ssrc[CAPH];
  int t = threadIdx.x;
  int b = blockIdx.x >> 1;
  int dlo = (blockIdx.x & 1) * HSZ;   // this WG's dst-range within the bucket
  int base = boff[b];
  int cnt  = cc[b];
  if (cnt > 12 * 512) cnt = 12 * 512;  // 6144 cap (astronomically safe)

  if (t < 128) lcnt[t] = 0;
  __syncthreads();

  // read the bucket's edges, keep those whose dl is in [dlo, dlo+HSZ)
  unsigned ce[12];
  #pragma unroll
  for (int j = 0; j < 12; j++) {
    int i = t + j * 512;
    ce[j] = 0xFFFFFFFFu;
    if (i < cnt) {
      unsigned e = cs[base + i];
      int dl = (int)(e >> 17);
      if (dl >= dlo && dl < dlo + HSZ) {
        ce[j] = e;
        atomicAdd(&lcnt[dl - dlo], 1);
      }
    }
  }
  __syncthreads();
  if (t < 128) loff[t] = lcnt[t];
  __syncthreads();
  for (int off = 1; off < 128; off <<= 1) {
    int v = 0;
    if (t < 128) { v = loff[t]; if (t >= off) v += loff[t - off]; }
    __syncthreads();
    if (t < 128) loff[t] = v;
    __syncthreads();
  }
  if (t < 128) { int ex = loff[t] - lcnt[t]; loff[t] = ex; lcur[t] = ex; }
  __syncthreads();
  #pragma unroll
  for (int j = 0; j < 12; j++) if (ce[j] != 0xFFFFFFFFu) {
    int p = atomicAdd(&lcur[(int)(ce[j] >> 17) - dlo], 1);
    if (p < CAPH) ssrc[p] = (int)(ce[j] & 0x1FFFFu);
  }
  __syncthreads();

  int wv = t >> 6;        // wave 0..7
  int l  = t & 63;
  int s  = l >> 2;        // dst slot within wave (0..15)
  int q  = l & 3;         // channel quad: channels 16q..16q+15, heads 2q,2q+1
  int d2 = s * 8 + wv;    // 0..127, balanced across waves

  if (d2 < HSZ) {
    int dst = b * BSZ + dlo + d2;

    // self weights for heads 2q, 2q+1
    float2 sa2 = __half22float2(*(const __half2*)(a_srch + dst * 8 + q * 2));
    float2 ad2 = *(const float2*)(a_dst + dst * 8 + q * 2);
    float z0 = sa2.x + ad2.x, z1 = sa2.y + ad2.y;
    float den0 = __expf(fmaxf(z0, 0.2f * z0));
    float den1 = __expf(fmaxf(z1, 0.2f * z1));

    // acc init = selfw * x_self (16 channels)
    uint4 xs = *(const uint4*)(xw8 + (size_t)dst * 64 + q * 16);
    float xv[16];
    cvt4(xs.x, xv); cvt4(xs.y, xv + 4); cvt4(xs.z, xv + 8); cvt4(xs.w, xv + 12);
    float acc[16];
    #pragma unroll
    for (int c = 0; c < 8; c++) { acc[c] = den0 * xv[c]; acc[8 + c] = den1 * xv[8 + c]; }

    int beg = loff[d2]; if (beg > CAPH) beg = CAPH;
    int end2 = beg + lcnt[d2]; if (end2 > CAPH) end2 = CAPH;

    // 2-deep rotation: indices from LDS, loads independent
    int nA = (beg < end2) ? ssrc[beg] : 0;
    int nB = (beg + 1 < end2) ? ssrc[beg + 1] : 0;
    __half2 aA = *(const __half2*)(a_srch + nA * 8 + q * 2);
    uint4   xA = *(const uint4*)(xw8 + (size_t)nA * 64 + q * 16);
    __half2 aB = *(const __half2*)(a_srch + nB * 8 + q * 2);
    uint4   xB = *(const uint4*)(xw8 + (size_t)nB * 64 + q * 16);

    for (int i = beg; i < end2; i++) {
      float2 af = __half22float2(aA);
      uint4  xc = xA;
      aA = aB; xA = xB;
      int nn = (i + 2 < end2) ? ssrc[i + 2] : 0;
      aB = *(const __half2*)(a_srch + nn * 8 + q * 2);
      xB = *(const uint4*)(xw8 + (size_t)nn * 64 + q * 16);

      float e0 = af.x + ad2.x, e1 = af.y + ad2.y;
      float w0 = __expf(fmaxf(e0, 0.2f * e0));
      float w1 = __expf(fmaxf(e1, 0.2f * e1));
      den0 += w0; den1 += w1;
      float yv[16];
      cvt4(xc.x, yv); cvt4(xc.y, yv + 4); cvt4(xc.z, yv + 8); cvt4(xc.w, yv + 12);
      #pragma unroll
      for (int c = 0; c < 8; c++) { acc[c] += w0 * yv[c]; acc[8 + c] += w1 * yv[8 + c]; }
    }

    // epilogue: divide, bias, relu, pack 16 bf16 = 32B
    float inv0 = __builtin_amdgcn_rcpf(den0);
    float inv1 = __builtin_amdgcn_rcpf(den1);
    uint4 bb0 = ((const uint4*)bias)[q * 2];
    uint4 bb1 = ((const uint4*)bias)[q * 2 + 1];
    unsigned bw[8] = {bb0.x, bb0.y, bb0.z, bb0.w, bb1.x, bb1.y, bb1.z, bb1.w};
    unsigned ow[8];
    #pragma unroll
    for (int p = 0; p < 8; p++) {
      float inv = (p < 4) ? inv0 : inv1;
      float v0 = acc[p * 2]     * inv + b2f((unsigned short)(bw[p] & 0xffff));
      float v1 = acc[p * 2 + 1] * inv + b2f((unsigned short)(bw[p] >> 16));
      v0 = fmaxf(v0, 0.f); v1 = fmaxf(v1, 0.f);
      ow[p] = (unsigned)f2b(v0) | ((unsigned)f2b(v1) << 16);
    }
    uint4 o0 = make_uint4(ow[0], ow[1], ow[2], ow[3]);
    uint4 o1 = make_uint4(ow[4], ow[5], ow[6], ow[7]);
    ((uint4*)nembh)[(size_t)dst * 8 + q * 2]     = o0;
    ((uint4*)nembh)[(size_t)dst * 8 + q * 2 + 1] = o1;
  }
}

// ---- K6: padded gather from bf16 nemb -> fp32 out + seq_lengths tail ----
__global__ __launch_bounds__(256) void k6_gather(
    const unsigned short* __restrict__ nembh, const int* __restrict__ traj,
    const int* __restrict__ lens, float* __restrict__ out)
{
  int gid = blockIdx.x * 256 + threadIdx.x;
  if (gid < BATCHC * MAXLENC * 16) {
    int b = gid >> 15;
    int rem = gid & 32767;
    int l = rem >> 4;
    int ch = rem & 15;
    int len = clampi(lens[b], 0, MAXLENC);
    float4 val = make_float4(0.f, 0.f, 0.f, 0.f);
    if (l < len) {
      int node = clampi(traj[b * MAXLENC + l], 0, N_NODESC - 1);
      uint2 q = ((const uint2*)nembh)[(size_t)node * 16 + ch];
      val = make_float4(b2f((unsigned short)(q.x & 0xffff)),
                        b2f((unsigned short)(q.x >> 16)),
                        b2f((unsigned short)(q.y & 0xffff)),
                        b2f((unsigned short)(q.y >> 16)));
    }
    ((float4*)out)[gid] = val;
  }
  if (gid < BATCHC) {
    out[(size_t)BATCHC * MAXLENC * FEATC + gid] = (float)lens[gid];
  }
}

extern "C" void kernel_launch(void* const* d_in, const int* in_sizes, int n_in,
                              void* d_out, int out_size, void* d_ws, size_t ws_size,
                              hipStream_t stream) {
  const unsigned short* x    = (const unsigned short*)d_in[0];
  const unsigned short* W    = (const unsigned short*)d_in[1];
  const unsigned short* attS = (const unsigned short*)d_in[2];
  const unsigned short* attD = (const unsigned short*)d_in[3];
  const unsigned short* bias = (const unsigned short*)d_in[4];
  const int* ei   = (const int*)d_in[5];
  const int* traj = (const int*)d_in[6];
  const int* lens = (const int*)d_in[7];
  float* out = (float*)d_out;

  // workspace (float units, max 9.9M floats = 39.6 MB; under proven size):
  //  [0, 1.6M)        xw fp8 (6.4M bytes)
  //  [3.2M, 3.6M)     a_src fp16 (800k half)
  //  [4.0M, 4.8M)     a_dst fp32
  //  [4.9M, +512)     ccounts (500)
  //  [+512, +1024)    gcur (500, zero-based)   -- one memset covers both
  //  [+1024, +1536)   boff (500, written by k_csort block 0)
  //  [5.0M, 6.6M)     cs (packed uint, 1.6M)
  //  [6.7M, 9.9M)     nemb bf16 (6.4M ushort)
  float* F = (float*)d_ws;
  unsigned char* xw8 = (unsigned char*)d_ws;
  __half* a_srch = (__half*)(F + 3200000);
  float* a_dst   = F + 4000000;
  int* ccounts   = (int*)(F + 4900000);
  int* gcur      = (int*)(F + 4900000) + 512;
  int* boff      = (int*)(F + 4900000) + 1024;
  unsigned* cs   = (unsigned*)(F + 5000000);
  unsigned short* nembh = (unsigned short*)(F + 6700000);

  hipMemsetAsync(ccounts, 0, 1024 * sizeof(int), stream);
  k_pre<<<K1B + (N_EDGESC / 4 + 255) / 256, 256, 0, stream>>>(
      x, W, attS, attD, ei, xw8, a_srch, a_dst, ccounts);
  k_csort<<<(N_EDGESC + P3_EDGES - 1) / P3_EDGES, 1024, 0, stream>>>(ei, ccounts, gcur, cs, boff);
  k_aggf<<<NBUCK * 2, 512, 0, stream>>>(a_srch, a_dst, xw8, cs, ccounts, boff, bias, nembh);
  k6_gather<<<(BATCHC * MAXLENC * 16 + 255) / 256, 256, 0, stream>>>(nembh, traj, lens, out);
}

// Round 9
// 172.701 us; speedup vs baseline: 4.4142x; 1.0676x over previous
//
#include <hip/hip_runtime.h>
#include <hip/hip_bf16.h>
#include <hip/hip_fp8.h>
#include <hip/hip_fp16.h>

#define N_NODESC 100000
#define N_EDGESC 1600000
#define FEATC 64
#define HEADSC 8
#define BATCHC 64
#define MAXLENC 2048
#define NBUCK 500          // 500 buckets x exactly 200 dst nodes
#define BSZ 200
#define HSZ 100            // dsts per k_aggf workgroup (half bucket)
#define CAPH 3072          // LDS edge capacity per half-bucket (mean 1600, sigma ~40)
#define P3_EDGES 8192      // edges per k_csort workgroup (1024 thr x 8)
#define K1B 782            // k_pre blocks doing the node transform (128 nodes each)
#define HCHUNK 16          // int4-chunks of 256 per histogram block
#define K2B 98             // histogram blocks: 98*16*256 = 401408 >= 400000 int4s

typedef float f32x2 __attribute__((ext_vector_type(2)));

__device__ __forceinline__ float b2f(unsigned short u){
  union { unsigned u; float f; } c; c.u = ((unsigned)u) << 16; return c.f;
}
__device__ __forceinline__ unsigned short f2b(float f){
  union { float f; unsigned u; } c; c.f = f;
  unsigned r = c.u + 0x7fffu + ((c.u >> 16) & 1u);
  return (unsigned short)(r >> 16);
}
__device__ __forceinline__ int clampi(int v, int lo, int hi){
  return v < lo ? lo : (v > hi ? hi : v);
}
__device__ __forceinline__ void unpack8(uint4 v, float* o){
  o[0] = b2f((unsigned short)(v.x & 0xffff)); o[1] = b2f((unsigned short)(v.x >> 16));
  o[2] = b2f((unsigned short)(v.y & 0xffff)); o[3] = b2f((unsigned short)(v.y >> 16));
  o[4] = b2f((unsigned short)(v.z & 0xffff)); o[5] = b2f((unsigned short)(v.z >> 16));
  o[6] = b2f((unsigned short)(v.w & 0xffff)); o[7] = b2f((unsigned short)(v.w >> 16));
}
// 4 x fp8(e4m3, OCP on gfx950) packed in a dword -> 4 floats via v_cvt_pk_f32_fp8
__device__ __forceinline__ void cvt4(unsigned v, float* o){
  f32x2 lo = __builtin_amdgcn_cvt_pk_f32_fp8((int)v, false);
  f32x2 hi = __builtin_amdgcn_cvt_pk_f32_fp8((int)v, true);
  o[0] = lo.x; o[1] = lo.y; o[2] = hi.x; o[3] = hi.y;
}

// ---- K_pre v3: heterogeneous grid. Blocks [0,K1B): xw=x@W -> fp8 + a_src
// (fp16) + a_dst(fp32), 128 nodes/block, 2 nodes/thread. Blocks [K1B,K1B+K2B):
// coarse 500-bin histogram, GRID-PERSISTENT: 98 blocks x 16 chunks instead of
// 1563 blocks -> global atomic flush drops 780K -> 49K adds (R8 postmortem:
// 1563 serialized atomics per cc[] address was the k_pre floor, not the
// transform). ----
__global__ __launch_bounds__(256) void k_pre(
    const unsigned short* __restrict__ x, const unsigned short* __restrict__ W,
    const unsigned short* __restrict__ attS, const unsigned short* __restrict__ attD,
    const int* __restrict__ ei,
    unsigned char* __restrict__ xw8, __half* __restrict__ a_srch,
    float* __restrict__ a_dst, int* __restrict__ cc)
{
  __shared__ float Wsf[64 * 64];
  __shared__ float as_s[64];
  __shared__ float ad_s[64];
  __shared__ int hh[NBUCK];
  int t = threadIdx.x;

  if (blockIdx.x >= K1B) {
    // ---- coarse histogram part (grid-persistent) ----
    for (int i = t; i < NBUCK; i += 256) hh[i] = 0;
    __syncthreads();
    int base4 = (blockIdx.x - K1B) * (HCHUNK * 256);
    #pragma unroll 4
    for (int it = 0; it < HCHUNK; it++) {
      int g = base4 + it * 256 + t;
      if (g < N_EDGESC / 4) {
        int4 d = ((const int4*)(ei + N_EDGESC))[g];
        atomicAdd(&hh[clampi(d.x, 0, N_NODESC - 1) / BSZ], 1);
        atomicAdd(&hh[clampi(d.y, 0, N_NODESC - 1) / BSZ], 1);
        atomicAdd(&hh[clampi(d.z, 0, N_NODESC - 1) / BSZ], 1);
        atomicAdd(&hh[clampi(d.w, 0, N_NODESC - 1) / BSZ], 1);
      }
    }
    __syncthreads();
    for (int i = t; i < NBUCK; i += 256) if (hh[i]) atomicAdd(&cc[i], hh[i]);
    return;
  }

  // ---- node transform part ----
  for (int i = t; i < 4096; i += 256) Wsf[i] = b2f(W[i]);
  if (t < 64) { as_s[t] = b2f(attS[t]); ad_s[t] = b2f(attD[t]); }
  __syncthreads();

  int g    = t & 3;
  int slot = t >> 2;
  int n0 = blockIdx.x * 128 + slot * 2;

  float acc[2][16];
  #pragma unroll
  for (int j = 0; j < 2; j++)
    #pragma unroll
    for (int c = 0; c < 16; c++) acc[j][c] = 0.f;

  const float4* Ws4 = (const float4*)Wsf;
  for (int i = 0; i < 8; i++) {
    float xu[2][8];
    #pragma unroll
    for (int j = 0; j < 2; j++) {
      int n = n0 + j;
      uint4 v = make_uint4(0u,0u,0u,0u);
      if (n < N_NODESC) v = ((const uint4*)(x + (size_t)n * 64))[i];
      unpack8(v, xu[j]);
    }
    #pragma unroll
    for (int u = 0; u < 8; u++) {
      int k = i * 8 + u;
      float4 w0 = Ws4[k * 16 + g * 4 + 0];
      float4 w1 = Ws4[k * 16 + g * 4 + 1];
      float4 w2 = Ws4[k * 16 + g * 4 + 2];
      float4 w3 = Ws4[k * 16 + g * 4 + 3];
      #pragma unroll
      for (int j = 0; j < 2; j++) {
        float xk = xu[j][u];
        acc[j][ 0] += xk * w0.x; acc[j][ 1] += xk * w0.y;
        acc[j][ 2] += xk * w0.z; acc[j][ 3] += xk * w0.w;
        acc[j][ 4] += xk * w1.x; acc[j][ 5] += xk * w1.y;
        acc[j][ 6] += xk * w1.z; acc[j][ 7] += xk * w1.w;
        acc[j][ 8] += xk * w2.x; acc[j][ 9] += xk * w2.y;
        acc[j][10] += xk * w2.z; acc[j][11] += xk * w2.w;
        acc[j][12] += xk * w3.x; acc[j][13] += xk * w3.y;
        acc[j][14] += xk * w3.z; acc[j][15] += xk * w3.w;
      }
    }
  }

  #pragma unroll
  for (int j = 0; j < 2; j++) {
    int n = n0 + j;
    if (n >= N_NODESC) break;
    union { unsigned u[4]; unsigned char b[16]; } pk;
    #pragma unroll
    for (int c = 0; c < 16; c++)
      pk.b[c] = (unsigned char)__hip_fp8_e4m3(acc[j][c]).__x;
    uint4 o; o.x = pk.u[0]; o.y = pk.u[1]; o.z = pk.u[2]; o.w = pk.u[3];
    *((uint4*)(xw8 + (size_t)n * 64 + g * 16)) = o;

    #pragma unroll
    for (int hl = 0; hl < 2; hl++) {
      int h = g * 2 + hl;
      float sa = 0.f, sd = 0.f;
      #pragma unroll
      for (int c = 0; c < 8; c++) {
        sa += acc[j][hl * 8 + c] * as_s[h * 8 + c];
        sd += acc[j][hl * 8 + c] * ad_s[h * 8 + c];
      }
      a_srch[n * 8 + h] = __float2half(sa);
      a_dst[n * 8 + h] = sd;
    }
  }
}

// ---- coarse scatter (1024 thr, 8192 edges/wg): self-scan of cc -> bstart,
// LDS counting-sort by bucket, contiguous run writes via zero-based gcur.
// Block 0 additionally publishes the exclusive bucket-prefix to boff[]. ----
__global__ __launch_bounds__(1024) void k_csort(const int* __restrict__ ei,
                                                const int* __restrict__ cc,
                                                int* __restrict__ gcur,
                                                unsigned* __restrict__ cs,
                                                int* __restrict__ boff) {
  __shared__ int bst[512];
  __shared__ int h[NBUCK], lst[NBUCK], lcur[NBUCK], gb[NBUCK];
  __shared__ int sc[512];
  __shared__ unsigned sorted[P3_EDGES];
  __shared__ unsigned short sbk[P3_EDGES];
  int t = threadIdx.x;
  int base = blockIdx.x * P3_EDGES;
  for (int i = t; i < NBUCK; i += 1024) h[i] = 0;
  int myc = 0;
  if (t < 512) { myc = (t < NBUCK) ? cc[t] : 0; bst[t] = myc; }
  __syncthreads();
  for (int off = 1; off < 512; off <<= 1) {
    int v = 0;
    if (t < 512) { v = bst[t]; if (t >= off) v += bst[t - off]; }
    __syncthreads();
    if (t < 512) bst[t] = v;
    __syncthreads();
  }
  if (blockIdx.x == 0 && t < NBUCK) boff[t] = bst[t] - myc;
  unsigned pk[8]; int bk[8];
  #pragma unroll
  for (int k = 0; k < 8; k++) {
    int idx = base + k * 1024 + t;
    bk[k] = -1;
    if (idx < N_EDGESC) {
      int s = clampi(ei[idx], 0, N_NODESC - 1);
      int d = clampi(ei[N_EDGESC + idx], 0, N_NODESC - 1);
      int b = d / BSZ;
      pk[k] = (unsigned)s | ((unsigned)(d - b * BSZ) << 17);
      bk[k] = b;
      atomicAdd(&h[b], 1);
    }
  }
  __syncthreads();
  if (t < 512) sc[t] = (t < NBUCK) ? h[t] : 0;
  __syncthreads();
  for (int off = 1; off < 512; off <<= 1) {
    int v = 0;
    if (t < 512) { v = sc[t]; if (t >= off) v += sc[t - off]; }
    __syncthreads();
    if (t < 512) sc[t] = v;
    __syncthreads();
  }
  if (t < NBUCK) {
    int ex = sc[t] - h[t];
    lst[t] = ex; lcur[t] = ex;
    if (h[t]) gb[t] = (bst[t] - myc) + atomicAdd(&gcur[t], h[t]);
  }
  __syncthreads();
  #pragma unroll
  for (int k = 0; k < 8; k++) if (bk[k] >= 0) {
    int p = atomicAdd(&lcur[bk[k]], 1);
    sorted[p] = pk[k];
    sbk[p] = (unsigned short)bk[k];
  }
  __syncthreads();
  int cnt = N_EDGESC - base; if (cnt > P3_EDGES) cnt = P3_EDGES;
  #pragma unroll
  for (int k = 0; k < 8; k++) {
    int i = k * 1024 + t;
    if (i < cnt) {
      int b = sbk[i];
      cs[gb[b] + (i - lst[b])] = sorted[i];
    }
  }
}

// ---- K_aggf v6: TWO 512-thread WGs per bucket (100 dsts each), 1000 WGs.
// FOUR lanes own one dst: lane = (dst-slot s=l>>2, quad q=l&3). Quad q covers
// channels 16q..16q+15 = heads 2q,2q+1, so each lane computes its own two
// edge weights -> ZERO cross-lane ops anywhere. Per edge per lane: one uint4
// xw8 load (4 lanes = full 64B row) + one half2 a_src load; 2-deep rotation.
__global__ __launch_bounds__(512) void k_aggf(
    const __half* __restrict__ a_srch, const float* __restrict__ a_dst,
    const unsigned char* __restrict__ xw8, const unsigned* __restrict__ cs,
    const int* __restrict__ cc, const int* __restrict__ boff,
    const unsigned short* __restrict__ bias, unsigned short* __restrict__ nembh)
{
  __shared__ int lcnt[128], loff[128], lcur[128];
  __shared__ int ssrc[CAPH];
  int t = threadIdx.x;
  int b = blockIdx.x >> 1;
  int dlo = (blockIdx.x & 1) * HSZ;   // this WG's dst-range within the bucket
  int base = boff[b];
  int cnt  = cc[b];
  if (cnt > 12 * 512) cnt = 12 * 512;  // 6144 cap (astronomically safe)

  if (t < 128) lcnt[t] = 0;
  __syncthreads();

  // read the bucket's edges, keep those whose dl is in [dlo, dlo+HSZ)
  unsigned ce[12];
  #pragma unroll
  for (int j = 0; j < 12; j++) {
    int i = t + j * 512;
    ce[j] = 0xFFFFFFFFu;
    if (i < cnt) {
      unsigned e = cs[base + i];
      int dl = (int)(e >> 17);
      if (dl >= dlo && dl < dlo + HSZ) {
        ce[j] = e;
        atomicAdd(&lcnt[dl - dlo], 1);
      }
    }
  }
  __syncthreads();
  if (t < 128) loff[t] = lcnt[t];
  __syncthreads();
  for (int off = 1; off < 128; off <<= 1) {
    int v = 0;
    if (t < 128) { v = loff[t]; if (t >= off) v += loff[t - off]; }
    __syncthreads();
    if (t < 128) loff[t] = v;
    __syncthreads();
  }
  if (t < 128) { int ex = loff[t] - lcnt[t]; loff[t] = ex; lcur[t] = ex; }
  __syncthreads();
  #pragma unroll
  for (int j = 0; j < 12; j++) if (ce[j] != 0xFFFFFFFFu) {
    int p = atomicAdd(&lcur[(int)(ce[j] >> 17) - dlo], 1);
    if (p < CAPH) ssrc[p] = (int)(ce[j] & 0x1FFFFu);
  }
  __syncthreads();

  int wv = t >> 6;        // wave 0..7
  int l  = t & 63;
  int s  = l >> 2;        // dst slot within wave (0..15)
  int q  = l & 3;         // channel quad: channels 16q..16q+15, heads 2q,2q+1
  int d2 = s * 8 + wv;    // 0..127, balanced across waves

  if (d2 < HSZ) {
    int dst = b * BSZ + dlo + d2;

    // self weights for heads 2q, 2q+1
    float2 sa2 = __half22float2(*(const __half2*)(a_srch + dst * 8 + q * 2));
    float2 ad2 = *(const float2*)(a_dst + dst * 8 + q * 2);
    float z0 = sa2.x + ad2.x, z1 = sa2.y + ad2.y;
    float den0 = __expf(fmaxf(z0, 0.2f * z0));
    float den1 = __expf(fmaxf(z1, 0.2f * z1));

    // acc init = selfw * x_self (16 channels)
    uint4 xs = *(const uint4*)(xw8 + (size_t)dst * 64 + q * 16);
    float xv[16];
    cvt4(xs.x, xv); cvt4(xs.y, xv + 4); cvt4(xs.z, xv + 8); cvt4(xs.w, xv + 12);
    float acc[16];
    #pragma unroll
    for (int c = 0; c < 8; c++) { acc[c] = den0 * xv[c]; acc[8 + c] = den1 * xv[8 + c]; }

    int beg = loff[d2]; if (beg > CAPH) beg = CAPH;
    int end2 = beg + lcnt[d2]; if (end2 > CAPH) end2 = CAPH;

    // 2-deep rotation: indices from LDS, loads independent
    int nA = (beg < end2) ? ssrc[beg] : 0;
    int nB = (beg + 1 < end2) ? ssrc[beg + 1] : 0;
    __half2 aA = *(const __half2*)(a_srch + nA * 8 + q * 2);
    uint4   xA = *(const uint4*)(xw8 + (size_t)nA * 64 + q * 16);
    __half2 aB = *(const __half2*)(a_srch + nB * 8 + q * 2);
    uint4   xB = *(const uint4*)(xw8 + (size_t)nB * 64 + q * 16);

    for (int i = beg; i < end2; i++) {
      float2 af = __half22float2(aA);
      uint4  xc = xA;
      aA = aB; xA = xB;
      int nn = (i + 2 < end2) ? ssrc[i + 2] : 0;
      aB = *(const __half2*)(a_srch + nn * 8 + q * 2);
      xB = *(const uint4*)(xw8 + (size_t)nn * 64 + q * 16);

      float e0 = af.x + ad2.x, e1 = af.y + ad2.y;
      float w0 = __expf(fmaxf(e0, 0.2f * e0));
      float w1 = __expf(fmaxf(e1, 0.2f * e1));
      den0 += w0; den1 += w1;
      float yv[16];
      cvt4(xc.x, yv); cvt4(xc.y, yv + 4); cvt4(xc.z, yv + 8); cvt4(xc.w, yv + 12);
      #pragma unroll
      for (int c = 0; c < 8; c++) { acc[c] += w0 * yv[c]; acc[8 + c] += w1 * yv[8 + c]; }
    }

    // epilogue: divide, bias, relu, pack 16 bf16 = 32B
    float inv0 = __builtin_amdgcn_rcpf(den0);
    float inv1 = __builtin_amdgcn_rcpf(den1);
    uint4 bb0 = ((const uint4*)bias)[q * 2];
    uint4 bb1 = ((const uint4*)bias)[q * 2 + 1];
    unsigned bw[8] = {bb0.x, bb0.y, bb0.z, bb0.w, bb1.x, bb1.y, bb1.z, bb1.w};
    unsigned ow[8];
    #pragma unroll
    for (int p = 0; p < 8; p++) {
      float inv = (p < 4) ? inv0 : inv1;
      float v0 = acc[p * 2]     * inv + b2f((unsigned short)(bw[p] & 0xffff));
      float v1 = acc[p * 2 + 1] * inv + b2f((unsigned short)(bw[p] >> 16));
      v0 = fmaxf(v0, 0.f); v1 = fmaxf(v1, 0.f);
      ow[p] = (unsigned)f2b(v0) | ((unsigned)f2b(v1) << 16);
    }
    uint4 o0 = make_uint4(ow[0], ow[1], ow[2], ow[3]);
    uint4 o1 = make_uint4(ow[4], ow[5], ow[6], ow[7]);
    ((uint4*)nembh)[(size_t)dst * 8 + q * 2]     = o0;
    ((uint4*)nembh)[(size_t)dst * 8 + q * 2 + 1] = o1;
  }
}

// ---- K6: padded gather from bf16 nemb -> fp32 out + seq_lengths tail ----
__global__ __launch_bounds__(256) void k6_gather(
    const unsigned short* __restrict__ nembh, const int* __restrict__ traj,
    const int* __restrict__ lens, float* __restrict__ out)
{
  int gid = blockIdx.x * 256 + threadIdx.x;
  if (gid < BATCHC * MAXLENC * 16) {
    int b = gid >> 15;
    int rem = gid & 32767;
    int l = rem >> 4;
    int ch = rem & 15;
    int len = clampi(lens[b], 0, MAXLENC);
    float4 val = make_float4(0.f, 0.f, 0.f, 0.f);
    if (l < len) {
      int node = clampi(traj[b * MAXLENC + l], 0, N_NODESC - 1);
      uint2 q = ((const uint2*)nembh)[(size_t)node * 16 + ch];
      val = make_float4(b2f((unsigned short)(q.x & 0xffff)),
                        b2f((unsigned short)(q.x >> 16)),
                        b2f((unsigned short)(q.y & 0xffff)),
                        b2f((unsigned short)(q.y >> 16)));
    }
    ((float4*)out)[gid] = val;
  }
  if (gid < BATCHC) {
    out[(size_t)BATCHC * MAXLENC * FEATC + gid] = (float)lens[gid];
  }
}

extern "C" void kernel_launch(void* const* d_in, const int* in_sizes, int n_in,
                              void* d_out, int out_size, void* d_ws, size_t ws_size,
                              hipStream_t stream) {
  const unsigned short* x    = (const unsigned short*)d_in[0];
  const unsigned short* W    = (const unsigned short*)d_in[1];
  const unsigned short* attS = (const unsigned short*)d_in[2];
  const unsigned short* attD = (const unsigned short*)d_in[3];
  const unsigned short* bias = (const unsigned short*)d_in[4];
  const int* ei   = (const int*)d_in[5];
  const int* traj = (const int*)d_in[6];
  const int* lens = (const int*)d_in[7];
  float* out = (float*)d_out;

  // workspace (float units, max 9.9M floats = 39.6 MB; under proven size):
  //  [0, 1.6M)        xw fp8 (6.4M bytes)
  //  [3.2M, 3.6M)     a_src fp16 (800k half)
  //  [4.0M, 4.8M)     a_dst fp32
  //  [4.9M, +512)     ccounts (500)
  //  [+512, +1024)    gcur (500, zero-based)   -- one memset covers both
  //  [+1024, +1536)   boff (500, written by k_csort block 0)
  //  [5.0M, 6.6M)     cs (packed uint, 1.6M)
  //  [6.7M, 9.9M)     nemb bf16 (6.4M ushort)
  float* F = (float*)d_ws;
  unsigned char* xw8 = (unsigned char*)d_ws;
  __half* a_srch = (__half*)(F + 3200000);
  float* a_dst   = F + 4000000;
  int* ccounts   = (int*)(F + 4900000);
  int* gcur      = (int*)(F + 4900000) + 512;
  int* boff      = (int*)(F + 4900000) + 1024;
  unsigned* cs   = (unsigned*)(F + 5000000);
  unsigned short* nembh = (unsigned short*)(F + 6700000);

  hipMemsetAsync(ccounts, 0, 1024 * sizeof(int), stream);
  k_pre<<<K1B + K2B, 256, 0, stream>>>(
      x, W, attS, attD, ei, xw8, a_srch, a_dst, ccounts);
  k_csort<<<(N_EDGESC + P3_EDGES - 1) / P3_EDGES, 1024, 0, stream>>>(ei, ccounts, gcur, cs, boff);
  k_aggf<<<NBUCK * 2, 512, 0, stream>>>(a_srch, a_dst, xw8, cs, ccounts, boff, bias, nembh);
  k6_gather<<<(BATCHC * MAXLENC * 16 + 255) / 256, 256, 0, stream>>>(nembh, traj, lens, out);
}

// Round 10
// 171.433 us; speedup vs baseline: 4.4469x; 1.0074x over previous
//
#include <hip/hip_runtime.h>
#include <hip/hip_bf16.h>
#include <hip/hip_fp8.h>
#include <hip/hip_fp16.h>

#define N_NODESC 100000
#define N_EDGESC 1600000
#define FEATC 64
#define HEADSC 8
#define BATCHC 64
#define MAXLENC 2048
#define NBUCK 500          // 500 buckets x exactly 200 dst nodes
#define BSZ 200
#define HSZ 100            // dsts per k_aggf workgroup (half bucket)
#define CAPH 3072          // LDS edge capacity per half-bucket (mean 1600, sigma ~40)
#define P3_EDGES 8192      // edges per k_csort workgroup (1024 thr x 8)
#define K1B 782            // k_pre blocks doing the node transform (128 nodes each)
#define HCHUNK 16          // int4-chunks of 256 per histogram block
#define K2B 98             // histogram blocks: 98*16*256 = 401408 >= 400000 int4s

typedef float f32x2 __attribute__((ext_vector_type(2)));

__device__ __forceinline__ float b2f(unsigned short u){
  union { unsigned u; float f; } c; c.u = ((unsigned)u) << 16; return c.f;
}
__device__ __forceinline__ unsigned short f2b(float f){
  union { float f; unsigned u; } c; c.f = f;
  unsigned r = c.u + 0x7fffu + ((c.u >> 16) & 1u);
  return (unsigned short)(r >> 16);
}
__device__ __forceinline__ int clampi(int v, int lo, int hi){
  return v < lo ? lo : (v > hi ? hi : v);
}
__device__ __forceinline__ void unpack8(uint4 v, float* o){
  o[0] = b2f((unsigned short)(v.x & 0xffff)); o[1] = b2f((unsigned short)(v.x >> 16));
  o[2] = b2f((unsigned short)(v.y & 0xffff)); o[3] = b2f((unsigned short)(v.y >> 16));
  o[4] = b2f((unsigned short)(v.z & 0xffff)); o[5] = b2f((unsigned short)(v.z >> 16));
  o[6] = b2f((unsigned short)(v.w & 0xffff)); o[7] = b2f((unsigned short)(v.w >> 16));
}
// 4 x fp8(e4m3, OCP on gfx950) packed in a dword -> 4 floats via v_cvt_pk_f32_fp8
__device__ __forceinline__ void cvt4(unsigned v, float* o){
  f32x2 lo = __builtin_amdgcn_cvt_pk_f32_fp8((int)v, false);
  f32x2 hi = __builtin_amdgcn_cvt_pk_f32_fp8((int)v, true);
  o[0] = lo.x; o[1] = lo.y; o[2] = hi.x; o[3] = hi.y;
}

// ---- K_pre v4: heterogeneous grid. Blocks [0,K1B): xw=x@W -> fp8 + a_src
// (fp16) + a_dst(fp32), 128 nodes/block, 2 nodes/thread.
// v4: x-chunk staged to LDS in one coalesced burst (row stride padded 8->9
// uint4 to break the slot-bank conflict), W kept in LDS as raw bf16 (2
// ds_read_b128 per k instead of 4 f32 float4s -> halves W LDS traffic).
// Inner loop is pure LDS+VALU: no global latency to hide (R8: VALUBusy 26%,
// loads serialized). Blocks [K1B,..): grid-persistent coarse histogram.
__global__ __launch_bounds__(256) void k_pre(
    const unsigned short* __restrict__ x, const unsigned short* __restrict__ W,
    const unsigned short* __restrict__ attS, const unsigned short* __restrict__ attD,
    const int* __restrict__ ei,
    unsigned char* __restrict__ xw8, __half* __restrict__ a_srch,
    float* __restrict__ a_dst, int* __restrict__ cc)
{
  __shared__ unsigned short Wh[64 * 64];      // W as raw bf16 (8 KB)
  __shared__ float as_s[64];
  __shared__ float ad_s[64];
  __shared__ uint4 xs_s[128 * 9];             // 128 node rows, 9-uint4 stride (18 KB)
  __shared__ int hh[NBUCK];
  int t = threadIdx.x;

  if (blockIdx.x >= K1B) {
    // ---- coarse histogram part (grid-persistent) ----
    for (int i = t; i < NBUCK; i += 256) hh[i] = 0;
    __syncthreads();
    int base4 = (blockIdx.x - K1B) * (HCHUNK * 256);
    #pragma unroll 4
    for (int it = 0; it < HCHUNK; it++) {
      int g = base4 + it * 256 + t;
      if (g < N_EDGESC / 4) {
        int4 d = ((const int4*)(ei + N_EDGESC))[g];
        atomicAdd(&hh[clampi(d.x, 0, N_NODESC - 1) / BSZ], 1);
        atomicAdd(&hh[clampi(d.y, 0, N_NODESC - 1) / BSZ], 1);
        atomicAdd(&hh[clampi(d.z, 0, N_NODESC - 1) / BSZ], 1);
        atomicAdd(&hh[clampi(d.w, 0, N_NODESC - 1) / BSZ], 1);
      }
    }
    __syncthreads();
    for (int i = t; i < NBUCK; i += 256) if (hh[i]) atomicAdd(&cc[i], hh[i]);
    return;
  }

  // ---- node transform part ----
  // stage W (bf16 raw) + att vectors + this block's 128-node x-chunk
  {
    const uint4* W4 = (const uint4*)W;
    ((uint4*)Wh)[t]       = W4[t];
    ((uint4*)Wh)[t + 256] = W4[t + 256];      // 512 uint4 = 4096 ushort
  }
  if (t < 64) { as_s[t] = b2f(attS[t]); ad_s[t] = b2f(attD[t]); }
  {
    const uint4* x4 = (const uint4*)x;        // 8 uint4 per node row
    int gbase = blockIdx.x * 1024;            // 128 nodes * 8
    #pragma unroll
    for (int r = 0; r < 4; r++) {
      int idx = t + r * 256;                  // 0..1023
      int nl = idx >> 3, i = idx & 7;
      uint4 v = make_uint4(0u, 0u, 0u, 0u);
      int gi = gbase + idx;
      if (gi < N_NODESC * 8) v = x4[gi];
      xs_s[nl * 9 + i] = v;
    }
  }
  __syncthreads();

  int g    = t & 3;
  int slot = t >> 2;
  int ln0  = slot * 2;                        // local node pair
  int n0   = blockIdx.x * 128 + ln0;

  float acc[2][16];
  #pragma unroll
  for (int j = 0; j < 2; j++)
    #pragma unroll
    for (int c = 0; c < 16; c++) acc[j][c] = 0.f;

  const uint4* Wq = (const uint4*)Wh;         // 8 uint4 per W row
  for (int i = 0; i < 8; i++) {
    float xu[2][8];
    #pragma unroll
    for (int j = 0; j < 2; j++) unpack8(xs_s[(ln0 + j) * 9 + i], xu[j]);
    #pragma unroll
    for (int u = 0; u < 8; u++) {
      int k = i * 8 + u;
      float wf[16];
      unpack8(Wq[k * 8 + g * 2 + 0], wf);
      unpack8(Wq[k * 8 + g * 2 + 1], wf + 8);
      #pragma unroll
      for (int j = 0; j < 2; j++) {
        float xk = xu[j][u];
        #pragma unroll
        for (int c = 0; c < 16; c++) acc[j][c] += xk * wf[c];
      }
    }
  }

  #pragma unroll
  for (int j = 0; j < 2; j++) {
    int n = n0 + j;
    if (n >= N_NODESC) break;
    union { unsigned u[4]; unsigned char b[16]; } pk;
    #pragma unroll
    for (int c = 0; c < 16; c++)
      pk.b[c] = (unsigned char)__hip_fp8_e4m3(acc[j][c]).__x;
    uint4 o; o.x = pk.u[0]; o.y = pk.u[1]; o.z = pk.u[2]; o.w = pk.u[3];
    *((uint4*)(xw8 + (size_t)n * 64 + g * 16)) = o;

    #pragma unroll
    for (int hl = 0; hl < 2; hl++) {
      int h = g * 2 + hl;
      float sa = 0.f, sd = 0.f;
      #pragma unroll
      for (int c = 0; c < 8; c++) {
        sa += acc[j][hl * 8 + c] * as_s[h * 8 + c];
        sd += acc[j][hl * 8 + c] * ad_s[h * 8 + c];
      }
      a_srch[n * 8 + h] = __float2half(sa);
      a_dst[n * 8 + h] = sd;
    }
  }
}

// ---- coarse scatter (1024 thr, 8192 edges/wg): self-scan of cc -> bstart,
// LDS counting-sort by bucket, contiguous run writes via zero-based gcur.
// Block 0 additionally publishes the exclusive bucket-prefix to boff[]. ----
__global__ __launch_bounds__(1024) void k_csort(const int* __restrict__ ei,
                                                const int* __restrict__ cc,
                                                int* __restrict__ gcur,
                                                unsigned* __restrict__ cs,
                                                int* __restrict__ boff) {
  __shared__ int bst[512];
  __shared__ int h[NBUCK], lst[NBUCK], lcur[NBUCK], gb[NBUCK];
  __shared__ int sc[512];
  __shared__ unsigned sorted[P3_EDGES];
  __shared__ unsigned short sbk[P3_EDGES];
  int t = threadIdx.x;
  int base = blockIdx.x * P3_EDGES;
  for (int i = t; i < NBUCK; i += 1024) h[i] = 0;
  int myc = 0;
  if (t < 512) { myc = (t < NBUCK) ? cc[t] : 0; bst[t] = myc; }
  __syncthreads();
  for (int off = 1; off < 512; off <<= 1) {
    int v = 0;
    if (t < 512) { v = bst[t]; if (t >= off) v += bst[t - off]; }
    __syncthreads();
    if (t < 512) bst[t] = v;
    __syncthreads();
  }
  if (blockIdx.x == 0 && t < NBUCK) boff[t] = bst[t] - myc;
  unsigned pk[8]; int bk[8];
  #pragma unroll
  for (int k = 0; k < 8; k++) {
    int idx = base + k * 1024 + t;
    bk[k] = -1;
    if (idx < N_EDGESC) {
      int s = clampi(ei[idx], 0, N_NODESC - 1);
      int d = clampi(ei[N_EDGESC + idx], 0, N_NODESC - 1);
      int b = d / BSZ;
      pk[k] = (unsigned)s | ((unsigned)(d - b * BSZ) << 17);
      bk[k] = b;
      atomicAdd(&h[b], 1);
    }
  }
  __syncthreads();
  if (t < 512) sc[t] = (t < NBUCK) ? h[t] : 0;
  __syncthreads();
  for (int off = 1; off < 512; off <<= 1) {
    int v = 0;
    if (t < 512) { v = sc[t]; if (t >= off) v += sc[t - off]; }
    __syncthreads();
    if (t < 512) sc[t] = v;
    __syncthreads();
  }
  if (t < NBUCK) {
    int ex = sc[t] - h[t];
    lst[t] = ex; lcur[t] = ex;
    if (h[t]) gb[t] = (bst[t] - myc) + atomicAdd(&gcur[t], h[t]);
  }
  __syncthreads();
  #pragma unroll
  for (int k = 0; k < 8; k++) if (bk[k] >= 0) {
    int p = atomicAdd(&lcur[bk[k]], 1);
    sorted[p] = pk[k];
    sbk[p] = (unsigned short)bk[k];
  }
  __syncthreads();
  int cnt = N_EDGESC - base; if (cnt > P3_EDGES) cnt = P3_EDGES;
  #pragma unroll
  for (int k = 0; k < 8; k++) {
    int i = k * 1024 + t;
    if (i < cnt) {
      int b = sbk[i];
      cs[gb[b] + (i - lst[b])] = sorted[i];
    }
  }
}

// ---- K_aggf v6: TWO 512-thread WGs per bucket (100 dsts each), 1000 WGs.
// FOUR lanes own one dst: lane = (dst-slot s=l>>2, quad q=l&3). Quad q covers
// channels 16q..16q+15 = heads 2q,2q+1, so each lane computes its own two
// edge weights -> ZERO cross-lane ops anywhere. Per edge per lane: one uint4
// xw8 load (4 lanes = full 64B row) + one half2 a_src load; 2-deep rotation.
__global__ __launch_bounds__(512) void k_aggf(
    const __half* __restrict__ a_srch, const float* __restrict__ a_dst,
    const unsigned char* __restrict__ xw8, const unsigned* __restrict__ cs,
    const int* __restrict__ cc, const int* __restrict__ boff,
    const unsigned short* __restrict__ bias, unsigned short* __restrict__ nembh)
{
  __shared__ int lcnt[128], loff[128], lcur[128];
  __shared__ int ssrc[CAPH];
  int t = threadIdx.x;
  int b = blockIdx.x >> 1;
  int dlo = (blockIdx.x & 1) * HSZ;   // this WG's dst-range within the bucket
  int base = boff[b];
  int cnt  = cc[b];
  if (cnt > 12 * 512) cnt = 12 * 512;  // 6144 cap (astronomically safe)

  if (t < 128) lcnt[t] = 0;
  __syncthreads();

  // read the bucket's edges, keep those whose dl is in [dlo, dlo+HSZ)
  unsigned ce[12];
  #pragma unroll
  for (int j = 0; j < 12; j++) {
    int i = t + j * 512;
    ce[j] = 0xFFFFFFFFu;
    if (i < cnt) {
      unsigned e = cs[base + i];
      int dl = (int)(e >> 17);
      if (dl >= dlo && dl < dlo + HSZ) {
        ce[j] = e;
        atomicAdd(&lcnt[dl - dlo], 1);
      }
    }
  }
  __syncthreads();
  if (t < 128) loff[t] = lcnt[t];
  __syncthreads();
  for (int off = 1; off < 128; off <<= 1) {
    int v = 0;
    if (t < 128) { v = loff[t]; if (t >= off) v += loff[t - off]; }
    __syncthreads();
    if (t < 128) loff[t] = v;
    __syncthreads();
  }
  if (t < 128) { int ex = loff[t] - lcnt[t]; loff[t] = ex; lcur[t] = ex; }
  __syncthreads();
  #pragma unroll
  for (int j = 0; j < 12; j++) if (ce[j] != 0xFFFFFFFFu) {
    int p = atomicAdd(&lcur[(int)(ce[j] >> 17) - dlo], 1);
    if (p < CAPH) ssrc[p] = (int)(ce[j] & 0x1FFFFu);
  }
  __syncthreads();

  int wv = t >> 6;        // wave 0..7
  int l  = t & 63;
  int s  = l >> 2;        // dst slot within wave (0..15)
  int q  = l & 3;         // channel quad: channels 16q..16q+15, heads 2q,2q+1
  int d2 = s * 8 + wv;    // 0..127, balanced across waves

  if (d2 < HSZ) {
    int dst = b * BSZ + dlo + d2;

    // self weights for heads 2q, 2q+1
    float2 sa2 = __half22float2(*(const __half2*)(a_srch + dst * 8 + q * 2));
    float2 ad2 = *(const float2*)(a_dst + dst * 8 + q * 2);
    float z0 = sa2.x + ad2.x, z1 = sa2.y + ad2.y;
    float den0 = __expf(fmaxf(z0, 0.2f * z0));
    float den1 = __expf(fmaxf(z1, 0.2f * z1));

    // acc init = selfw * x_self (16 channels)
    uint4 xs = *(const uint4*)(xw8 + (size_t)dst * 64 + q * 16);
    float xv[16];
    cvt4(xs.x, xv); cvt4(xs.y, xv + 4); cvt4(xs.z, xv + 8); cvt4(xs.w, xv + 12);
    float acc[16];
    #pragma unroll
    for (int c = 0; c < 8; c++) { acc[c] = den0 * xv[c]; acc[8 + c] = den1 * xv[8 + c]; }

    int beg = loff[d2]; if (beg > CAPH) beg = CAPH;
    int end2 = beg + lcnt[d2]; if (end2 > CAPH) end2 = CAPH;

    // 2-deep rotation: indices from LDS, loads independent
    int nA = (beg < end2) ? ssrc[beg] : 0;
    int nB = (beg + 1 < end2) ? ssrc[beg + 1] : 0;
    __half2 aA = *(const __half2*)(a_srch + nA * 8 + q * 2);
    uint4   xA = *(const uint4*)(xw8 + (size_t)nA * 64 + q * 16);
    __half2 aB = *(const __half2*)(a_srch + nB * 8 + q * 2);
    uint4   xB = *(const uint4*)(xw8 + (size_t)nB * 64 + q * 16);

    for (int i = beg; i < end2; i++) {
      float2 af = __half22float2(aA);
      uint4  xc = xA;
      aA = aB; xA = xB;
      int nn = (i + 2 < end2) ? ssrc[i + 2] : 0;
      aB = *(const __half2*)(a_srch + nn * 8 + q * 2);
      xB = *(const uint4*)(xw8 + (size_t)nn * 64 + q * 16);

      float e0 = af.x + ad2.x, e1 = af.y + ad2.y;
      float w0 = __expf(fmaxf(e0, 0.2f * e0));
      float w1 = __expf(fmaxf(e1, 0.2f * e1));
      den0 += w0; den1 += w1;
      float yv[16];
      cvt4(xc.x, yv); cvt4(xc.y, yv + 4); cvt4(xc.z, yv + 8); cvt4(xc.w, yv + 12);
      #pragma unroll
      for (int c = 0; c < 8; c++) { acc[c] += w0 * yv[c]; acc[8 + c] += w1 * yv[8 + c]; }
    }

    // epilogue: divide, bias, relu, pack 16 bf16 = 32B
    float inv0 = __builtin_amdgcn_rcpf(den0);
    float inv1 = __builtin_amdgcn_rcpf(den1);
    uint4 bb0 = ((const uint4*)bias)[q * 2];
    uint4 bb1 = ((const uint4*)bias)[q * 2 + 1];
    unsigned bw[8] = {bb0.x, bb0.y, bb0.z, bb0.w, bb1.x, bb1.y, bb1.z, bb1.w};
    unsigned ow[8];
    #pragma unroll
    for (int p = 0; p < 8; p++) {
      float inv = (p < 4) ? inv0 : inv1;
      float v0 = acc[p * 2]     * inv + b2f((unsigned short)(bw[p] & 0xffff));
      float v1 = acc[p * 2 + 1] * inv + b2f((unsigned short)(bw[p] >> 16));
      v0 = fmaxf(v0, 0.f); v1 = fmaxf(v1, 0.f);
      ow[p] = (unsigned)f2b(v0) | ((unsigned)f2b(v1) << 16);
    }
    uint4 o0 = make_uint4(ow[0], ow[1], ow[2], ow[3]);
    uint4 o1 = make_uint4(ow[4], ow[5], ow[6], ow[7]);
    ((uint4*)nembh)[(size_t)dst * 8 + q * 2]     = o0;
    ((uint4*)nembh)[(size_t)dst * 8 + q * 2 + 1] = o1;
  }
}

// ---- K6: padded gather from bf16 nemb -> fp32 out + seq_lengths tail ----
__global__ __launch_bounds__(256) void k6_gather(
    const unsigned short* __restrict__ nembh, const int* __restrict__ traj,
    const int* __restrict__ lens, float* __restrict__ out)
{
  int gid = blockIdx.x * 256 + threadIdx.x;
  if (gid < BATCHC * MAXLENC * 16) {
    int b = gid >> 15;
    int rem = gid & 32767;
    int l = rem >> 4;
    int ch = rem & 15;
    int len = clampi(lens[b], 0, MAXLENC);
    float4 val = make_float4(0.f, 0.f, 0.f, 0.f);
    if (l < len) {
      int node = clampi(traj[b * MAXLENC + l], 0, N_NODESC - 1);
      uint2 q = ((const uint2*)nembh)[(size_t)node * 16 + ch];
      val = make_float4(b2f((unsigned short)(q.x & 0xffff)),
                        b2f((unsigned short)(q.x >> 16)),
                        b2f((unsigned short)(q.y & 0xffff)),
                        b2f((unsigned short)(q.y >> 16)));
    }
    ((float4*)out)[gid] = val;
  }
  if (gid < BATCHC) {
    out[(size_t)BATCHC * MAXLENC * FEATC + gid] = (float)lens[gid];
  }
}

extern "C" void kernel_launch(void* const* d_in, const int* in_sizes, int n_in,
                              void* d_out, int out_size, void* d_ws, size_t ws_size,
                              hipStream_t stream) {
  const unsigned short* x    = (const unsigned short*)d_in[0];
  const unsigned short* W    = (const unsigned short*)d_in[1];
  const unsigned short* attS = (const unsigned short*)d_in[2];
  const unsigned short* attD = (const unsigned short*)d_in[3];
  const unsigned short* bias = (const unsigned short*)d_in[4];
  const int* ei   = (const int*)d_in[5];
  const int* traj = (const int*)d_in[6];
  const int* lens = (const int*)d_in[7];
  float* out = (float*)d_out;

  // workspace (float units, max 9.9M floats = 39.6 MB; under proven size):
  //  [0, 1.6M)        xw fp8 (6.4M bytes)
  //  [3.2M, 3.6M)     a_src fp16 (800k half)
  //  [4.0M, 4.8M)     a_dst fp32
  //  [4.9M, +512)     ccounts (500)
  //  [+512, +1024)    gcur (500, zero-based)   -- one memset covers both
  //  [+1024, +1536)   boff (500, written by k_csort block 0)
  //  [5.0M, 6.6M)     cs (packed uint, 1.6M)
  //  [6.7M, 9.9M)     nemb bf16 (6.4M ushort)
  float* F = (float*)d_ws;
  unsigned char* xw8 = (unsigned char*)d_ws;
  __half* a_srch = (__half*)(F + 3200000);
  float* a_dst   = F + 4000000;
  int* ccounts   = (int*)(F + 4900000);
  int* gcur      = (int*)(F + 4900000) + 512;
  int* boff      = (int*)(F + 4900000) + 1024;
  unsigned* cs   = (unsigned*)(F + 5000000);
  unsigned short* nembh = (unsigned short*)(F + 6700000);

  hipMemsetAsync(ccounts, 0, 1024 * sizeof(int), stream);
  k_pre<<<K1B + K2B, 256, 0, stream>>>(
      x, W, attS, attD, ei, xw8, a_srch, a_dst, ccounts);
  k_csort<<<(N_EDGESC + P3_EDGES - 1) / P3_EDGES, 1024, 0, stream>>>(ei, ccounts, gcur, cs, boff);
  k_aggf<<<NBUCK * 2, 512, 0, stream>>>(a_srch, a_dst, xw8, cs, ccounts, boff, bias, nembh);
  k6_gather<<<(BATCHC * MAXLENC * 16 + 255) / 256, 256, 0, stream>>>(nembh, traj, lens, out);
}